// Round 9
// baseline (525.379 us; speedup 1.0000x reference)
//
#include <hip/hip_runtime.h>
#include <hip/hip_bf16.h>
#include <stdint.h>

// Problem constants
#define CC   384          // EMBED_DIM
#define BB   8
#define PP   4
#define NNN  4096
#define NBP  32           // B*P slices
#define PN   (PP*NNN)     // stride between channels in x/out (=16384 floats)

#define AS1 __attribute__((address_space(1)))
#define AS3 __attribute__((address_space(3)))

typedef float  f32x4 __attribute__((ext_vector_type(4)));
typedef short  s16x8 __attribute__((ext_vector_type(8)));
typedef unsigned short u16x4 __attribute__((ext_vector_type(4)));

__device__ __forceinline__ unsigned short f2bf(float f) {
  unsigned int u = __float_as_uint(f);
  u += 0x7fffu + ((u >> 16) & 1u);
  return (unsigned short)(u >> 16);
}
__device__ __forceinline__ float bf2f(unsigned short u) {
  return __uint_as_float(((unsigned int)u) << 16);
}

// Image swizzle: nonlinear in low row bits so both 16-consecutive-row reads
// (consumer) and stride-4-row writes (producer) spread over 8 bank groups.
__device__ __forceinline__ int swz16(int r) {
  return ((r ^ (r >> 2)) & 15) << 4;
}

// async global->LDS, 16B per lane. g is per-lane, l is wave-uniform base.
__device__ __forceinline__ void stage16(const char* g, char* l_uniform, int lane) {
#if defined(__has_builtin) && __has_builtin(__builtin_amdgcn_global_load_lds)
  __builtin_amdgcn_global_load_lds((const AS1 unsigned int*)g,
                                   (AS3 unsigned int*)l_uniform, 16, 0, 0);
#else
  *(int4*)(l_uniform + lane*16) = *(const int4*)g;
#endif
}

// ===========================================================================
// ============================ FAST PATH ====================================
// ===========================================================================

// K_PRE: per (bp, 64-n tile): transpose x -> swz16-swizzled bf16 LDS image
// (row r = local n, 768B/row), write 48KB to xbf[bid]; fold q-partials
// (q = w_q . x, fp32) in the same pass. grid=2048, block=256.
__global__ __launch_bounds__(256) void k_pre(
    const float* __restrict__ x, const float* __restrict__ wqkv,
    unsigned short* __restrict__ xbf, float* __restrict__ q)
{
  __shared__ __align__(16) unsigned short tr[24576];   // 48KB image
  __shared__ float4 qw[64];
  char* trb = (char*)tr;
  const int bid = blockIdx.x;
  const int bp = bid >> 6, nt = bid & 63;
  const int b = bp >> 2, p = bp & 3;
  const int n0 = nt * 64;
  const int t  = threadIdx.x;
  const int wv_ = t >> 6, lane = t & 63;
  const int cg = t >> 4, nv = t & 15;     // c-pair group 0..15, n-subvec 0..15
  const int r0 = 4 * nv;
  const float* xb = x + (size_t)b*CC*PN + (size_t)p*NNN + n0 + r0;
  const int s0 = swz16(r0+0), s1 = swz16(r0+1), s2 = swz16(r0+2), s3 = swz16(r0+3);

  float4 qa = {0.f, 0.f, 0.f, 0.f};
  #pragma unroll 3
  for (int it = 0; it < 12; ++it) {
    const int c0 = 32*it + 2*cg;
    const float4 x0 = *(const float4*)(xb + (size_t)c0*PN);
    const float4 x1 = *(const float4*)(xb + (size_t)(c0+1)*PN);
    const float w0 = wqkv[c0], w1 = wqkv[c0+1];
    qa.x += w0*x0.x + w1*x1.x;
    qa.y += w0*x0.y + w1*x1.y;
    qa.z += w0*x0.z + w1*x1.z;
    qa.w += w0*x0.w + w1*x1.w;
    const unsigned int p0 = (unsigned)f2bf(x0.x) | ((unsigned)f2bf(x1.x) << 16);
    const unsigned int p1 = (unsigned)f2bf(x0.y) | ((unsigned)f2bf(x1.y) << 16);
    const unsigned int p2 = (unsigned)f2bf(x0.z) | ((unsigned)f2bf(x1.z) << 16);
    const unsigned int p3 = (unsigned)f2bf(x0.w) | ((unsigned)f2bf(x1.w) << 16);
    const int cb = 2*c0;
    *(unsigned int*)(trb + (((r0+0)*768 + cb) ^ s0)) = p0;
    *(unsigned int*)(trb + (((r0+1)*768 + cb) ^ s1)) = p1;
    *(unsigned int*)(trb + (((r0+2)*768 + cb) ^ s2)) = p2;
    *(unsigned int*)(trb + (((r0+3)*768 + cb) ^ s3)) = p3;
  }
  // reduce q over the 16 c-groups: lanes differ in bits 4,5 within wave
  qa.x += __shfl_xor(qa.x, 16); qa.y += __shfl_xor(qa.y, 16);
  qa.z += __shfl_xor(qa.z, 16); qa.w += __shfl_xor(qa.w, 16);
  qa.x += __shfl_xor(qa.x, 32); qa.y += __shfl_xor(qa.y, 32);
  qa.z += __shfl_xor(qa.z, 32); qa.w += __shfl_xor(qa.w, 32);
  if (lane < 16) qw[wv_*16 + lane] = qa;
  __syncthreads();
  // copy image out (coalesced 16B)
  const int4* trs = (const int4*)tr;
  int4* dst = (int4*)(xbf + (size_t)bid * 24576);
  #pragma unroll
  for (int j = 0; j < 12; ++j) dst[j*256 + t] = trs[j*256 + t];
  if (t < 16) {
    float4 a0 = qw[t], a1 = qw[16+t], a2 = qw[32+t], a3 = qw[48+t];
    float4 o; o.x = a0.x+a1.x+a2.x+a3.x; o.y = a0.y+a1.y+a2.y+a3.y;
    o.z = a0.z+a1.z+a2.z+a3.z; o.w = a0.w+a1.w+a2.w+a3.w;
    *(float4*)(q + (size_t)bp*NNN + n0 + 4*t) = o;
  }
}

// K_WCVT2: W_v & W_out -> bf16, fragment-major tiling:
// idx(mf,ks,l15,g,j) = (mf*12+ks)*512 + l15*32 + g*8 + j ; row=16mf+l15, col=32ks+8g+j
__global__ __launch_bounds__(256) void k_wcvt2(
    const float* __restrict__ wqkv, const float* __restrict__ wout,
    unsigned short* __restrict__ wvt, unsigned short* __restrict__ woutt)
{
  const int i = blockIdx.x*256 + threadIdx.x;   // 0..294911
  const int e = (i < CC*CC) ? i : i - CC*CC;
  const int j   = e & 7;
  const int g   = (e >> 3) & 3;
  const int l15 = (e >> 5) & 15;
  const int rem = e >> 9;          // 0..287
  const int ks  = rem % 12;
  const int mf  = rem / 12;
  const int row = 16*mf + l15;
  const int col = 32*ks + 8*g + j;
  if (i < CC*CC) wvt[e]          = f2bf(wqkv[(size_t)(385 + row)*CC + col]);
  else           woutt[e]        = f2bf(wout[(size_t)row*CC + col]);
}

// K_SOFTMAX2: softmax over n per bp. grid=32, block=256.
__global__ __launch_bounds__(256) void k_softmax2(
    const float* __restrict__ q, const float* __restrict__ bqkv,
    float* __restrict__ scores)
{
  __shared__ float red[8];
  const int bp = blockIdx.x;
  const int t  = threadIdx.x;
  const int wv_ = t >> 6, ln = t & 63;
  const float bq = bqkv[0];
  float4 qv[4];
  float lmax = -1e30f;
  #pragma unroll
  for (int i = 0; i < 4; ++i) {
    const int n = i*1024 + t*4;
    float4 a = *(const float4*)(q + (size_t)bp*NNN + n);
    qv[i].x = a.x + bq; qv[i].y = a.y + bq; qv[i].z = a.z + bq; qv[i].w = a.w + bq;
    lmax = fmaxf(lmax, fmaxf(fmaxf(qv[i].x, qv[i].y), fmaxf(qv[i].z, qv[i].w)));
  }
  #pragma unroll
  for (int off = 32; off; off >>= 1) lmax = fmaxf(lmax, __shfl_xor(lmax, off));
  if (ln == 0) red[wv_] = lmax;
  __syncthreads();
  const float M = fmaxf(fmaxf(red[0], red[1]), fmaxf(red[2], red[3]));
  float lsum = 0.f;
  #pragma unroll
  for (int i = 0; i < 4; ++i) {
    qv[i].x = expf(qv[i].x - M); qv[i].y = expf(qv[i].y - M);
    qv[i].z = expf(qv[i].z - M); qv[i].w = expf(qv[i].w - M);
    lsum += qv[i].x + qv[i].y + qv[i].z + qv[i].w;
  }
  #pragma unroll
  for (int off = 32; off; off >>= 1) lsum += __shfl_xor(lsum, off);
  if (ln == 0) red[4 + wv_] = lsum;
  __syncthreads();
  const float inv = 1.f / (red[4] + red[5] + red[6] + red[7]);
  #pragma unroll
  for (int i = 0; i < 4; ++i) {
    const int n = i*1024 + t*4;
    float4 o; o.x=qv[i].x*inv; o.y=qv[i].y*inv; o.z=qv[i].z*inv; o.w=qv[i].w*inv;
    *(float4*)(scores + (size_t)bp*NNN + n) = o;
  }
}

// K_XS2: per (bp, tile): partial[bid][c] = sum_r xbf(r,c) * s[r]. grid=2048, block=384.
__global__ __launch_bounds__(384) void k_xs2(
    const unsigned short* __restrict__ xbf, const float* __restrict__ scores,
    float* __restrict__ partial)
{
  __shared__ __align__(16) char lds[49152];
  __shared__ float sl[64];
  const int bid = blockIdx.x;
  const int bp = bid >> 6, nt = bid & 63;
  const int t = threadIdx.x;
  const int w6 = t >> 6, lane = t & 63;
  const char* gsrc = (const char*)xbf + (size_t)bid * 49152;
  #pragma unroll
  for (int r = 0; r < 8; ++r) {
    const int loff = (r*6 + w6) * 1024;
    stage16(gsrc + loff + lane*16, lds + loff, lane);
  }
  if (t < 64) sl[t] = scores[(size_t)bp*NNN + nt*64 + t];
  __syncthreads();
  float acc = 0.f;
  #pragma unroll 8
  for (int r = 0; r < 64; ++r) {
    const unsigned short uv = *(const unsigned short*)(lds + ((r*768 + 2*t) ^ swz16(r)));
    acc += bf2f(uv) * sl[r];
  }
  partial[(size_t)bid*CC + t] = acc;
}

// K_CV2: xs[c] = sum_nt partial ; cv[bp][c] = b_k[c] + W_k[c].xs. grid=32, block=384.
__global__ __launch_bounds__(384) void k_cv2(
    const float* __restrict__ partial, const float* __restrict__ wqkv,
    const float* __restrict__ bqkv, float* __restrict__ cv)
{
  __shared__ float xsl[CC];
  const int bp = blockIdx.x;
  const int t  = threadIdx.x;
  float s = 0.f;
  #pragma unroll 8
  for (int nt = 0; nt < 64; ++nt) s += partial[((size_t)bp*64 + nt)*CC + t];
  xsl[t] = s;
  __syncthreads();
  float acc = bqkv[1 + t];
  const float* wk = wqkv + (size_t)(1 + t)*CC;
  #pragma unroll 8
  for (int c2 = 0; c2 < CC; ++c2) acc += wk[c2] * xsl[c2];
  cv[(size_t)bp*CC + t] = acc;
}

// K_MAIN4: pipelined fused double GEMM, 4 tiles/block, ping-pong LDS.
// 512 blocks x 512 thr; LDS = 2 x 48KB images. A streamed from fragment-major
// W (L2) with 3-deep rolling prefetch (low VGPR). Stage of tile j+1 is issued
// before GEMM1(j) so HBM latency hides under MFMA.
__device__ __forceinline__ void stage_tile(const char* gsrc, char* img, int w, int lane) {
  #pragma unroll
  for (int r = 0; r < 6; ++r) {
    const int loff = (r*8 + w) * 1024;
    stage16(gsrc + loff + lane*16, img + loff, lane);
  }
}

__device__ __forceinline__ void gemm_t(
    const unsigned short* __restrict__ wt, const char* lds,
    int w, int g, int l15, f32x4 acc[3][4])
{
  // per-wave fragment base: mf = 3w + mi ; A(mi,ks) at base + (mi*12+ks)*512
  const unsigned short* base = wt + (size_t)(3*w)*12*512 + l15*32 + g*8;
  s16x8 a[3][3];   // [slot = ks%3][mi]
  #pragma unroll
  for (int pf = 0; pf < 3; ++pf)
    #pragma unroll
    for (int mi = 0; mi < 3; ++mi)
      a[pf][mi] = *(const s16x8*)(base + ((size_t)mi*12 + pf)*512);
  #pragma unroll
  for (int ks = 0; ks < 12; ++ks) {
    const int slot = ks % 3;
    s16x8 bfr[4];
    #pragma unroll
    for (int nt = 0; nt < 4; ++nt) {
      const int row = 16*nt + l15;
      const int byteb = (row*768 + 64*ks + 16*g) ^ swz16(row);
      bfr[nt] = *(const s16x8*)(lds + byteb);
    }
    #pragma unroll
    for (int mi = 0; mi < 3; ++mi)
      #pragma unroll
      for (int nt = 0; nt < 4; ++nt)
        acc[mi][nt] = __builtin_amdgcn_mfma_f32_16x16x32_bf16(
            a[slot][mi], bfr[nt], acc[mi][nt], 0, 0, 0);
    if (ks + 3 < 12) {
      #pragma unroll
      for (int mi = 0; mi < 3; ++mi)
        a[slot][mi] = *(const s16x8*)(base + ((size_t)mi*12 + ks + 3)*512);
    }
  }
}

__global__ __launch_bounds__(512, 2) void k_main4(
    const unsigned short* __restrict__ xbf,
    const unsigned short* __restrict__ wvt,
    const unsigned short* __restrict__ woutt,
    const float* __restrict__ cv,
    const float* __restrict__ bqkv,
    const float* __restrict__ bout,
    float* __restrict__ out)
{
  __shared__ __align__(16) char lds[98304];   // 2 x 48KB ping-pong images
  const int bid = blockIdx.x;          // 0..511
  const int bp  = bid >> 4;            // 0..31 (4 consecutive tiles share bp)
  const int b = bp >> 2, p = bp & 3;
  const int tid = threadIdx.x;
  const int w = tid >> 6, lane = tid & 63, g = lane >> 4, l15 = lane & 15;
  const float* cvp = cv + (size_t)bp*CC;

  const char* gbase = (const char*)xbf + (size_t)(bid*4) * 49152;
  stage_tile(gbase, lds, w, lane);     // tile 0 -> buf0
  __syncthreads();

  #pragma unroll 1
  for (int j = 0; j < 4; ++j) {
    char* const imgc = lds + (j & 1) * 49152;
    char* const imgn = lds + ((j & 1) ^ 1) * 49152;
    if (j < 3) stage_tile(gbase + (size_t)(j+1)*49152, imgn, w, lane);

    f32x4 acc[3][4];
    #pragma unroll
    for (int i = 0; i < 3; ++i)
      #pragma unroll
      for (int k = 0; k < 4; ++k) acc[i][k] = (f32x4){0.f,0.f,0.f,0.f};

    // ---- GEMM1: v = W_v @ x  (stage(j+1) in flight underneath)
    gemm_t(wvt, imgc, w, g, l15, acc);
    __syncthreads();

    // ---- epi1: relu(v + b_v) * cv -> bf16 back into imgc
    #pragma unroll
    for (int mi = 0; mi < 3; ++mi) {
      const int m0 = 48*w + 16*mi + 4*g;
      const float* bv = bqkv + 385 + m0;
      const float b0 = bv[0], b1 = bv[1], b2 = bv[2], b3 = bv[3];
      const float4 cvv = *(const float4*)(cvp + m0);
      #pragma unroll
      for (int nt = 0; nt < 4; ++nt) {
        const int row = 16*nt + l15;
        const f32x4 t = acc[mi][nt];
        u16x4 pk = { f2bf(fmaxf(t[0]+b0, 0.f)*cvv.x), f2bf(fmaxf(t[1]+b1, 0.f)*cvv.y),
                     f2bf(fmaxf(t[2]+b2, 0.f)*cvv.z), f2bf(fmaxf(t[3]+b3, 0.f)*cvv.w) };
        const int byte0 = (row*768 + 2*m0) ^ swz16(row);
        *(u16x4*)(imgc + byte0) = pk;
      }
    }
    __syncthreads();

    #pragma unroll
    for (int i = 0; i < 3; ++i)
      #pragma unroll
      for (int k = 0; k < 4; ++k) acc[i][k] = (f32x4){0.f,0.f,0.f,0.f};

    // ---- GEMM2: out = W_out @ v
    gemm_t(woutt, imgc, w, g, l15, acc);

    // ---- epi2: +b_out, col-split LDS transpose in imgc ([384][32] fp32),
    //      coalesced 128B float4 stores.
    float* fl = (float*)imgc;
    const int n0 = ((bid & 15)*4 + j) * 64;
    float* outb = out + (size_t)b*CC*PN + (size_t)p*NNN + n0;
    #pragma unroll
    for (int half = 0; half < 2; ++half) {
      __syncthreads();   // GEMM2 reads of imgc done / prev half drained
      #pragma unroll
      for (int mi = 0; mi < 3; ++mi) {
        const int m0 = 48*w + 16*mi + 4*g;
        const float4 bo = *(const float4*)(bout + m0);
        #pragma unroll
        for (int nt2 = 0; nt2 < 2; ++nt2) {
          const f32x4 t = acc[mi][2*half + nt2];
          const int colh = 16*nt2 + l15;           // 0..31 within half
          fl[(m0+0)*32 + colh] = t[0] + bo.x;
          fl[(m0+1)*32 + colh] = t[1] + bo.y;
          fl[(m0+2)*32 + colh] = t[2] + bo.z;
          fl[(m0+3)*32 + colh] = t[3] + bo.w;
        }
      }
      __syncthreads();
      // drain 384x32 fp32: 512 threads x float4 x 6 passes; 8 lanes = 128B
      #pragma unroll
      for (int ps = 0; ps < 6; ++ps) {
        const int idx = ps*512 + tid;              // 0..3071 float4 slots
        const int row = idx >> 3;
        const int nq  = idx & 7;
        const float4 v = *(const float4*)(fl + row*32 + nq*4);
        *(float4*)(outb + (size_t)row*PN + 32*half + nq*4) = v;
      }
    }
    __syncthreads();   // drain LDS-reads done before imgc is re-staged (j+2)
  }
}

// ===========================================================================
// ========================= FALLBACK PATH (R3) ==============================
// ===========================================================================

__global__ __launch_bounds__(256) void k_qpart(
    const float* __restrict__ x, const float* __restrict__ wqkv,
    float* __restrict__ qpart)
{
  const int bid = blockIdx.x;
  const int seg = bid & 3;
  const int nc  = (bid >> 2) & 3;
  const int bp  = bid >> 4;
  const int b = bp >> 2, p = bp & 3;
  const int n = nc * 1024 + threadIdx.x * 4;
  const float* xb = x + (size_t)b*CC*PN + (size_t)p*NNN + n;
  float ax = 0.f, ay = 0.f, az = 0.f, aw = 0.f;
  const int c0 = seg * 96;
  #pragma unroll 8
  for (int c = c0; c < c0 + 96; ++c) {
    const float w = wqkv[c];
    const float4 xv = *(const float4*)(xb + (size_t)c*PN);
    ax += w*xv.x; ay += w*xv.y; az += w*xv.z; aw += w*xv.w;
  }
  float4 o; o.x=ax; o.y=ay; o.z=az; o.w=aw;
  *(float4*)(qpart + (size_t)(seg*NBP + bp)*NNN + n) = o;
}

__global__ __launch_bounds__(256) void k_softmax(
    const float* __restrict__ qpart, const float* __restrict__ bqkv,
    float* __restrict__ scores)
{
  __shared__ float red[8];
  const int bp = blockIdx.x;
  const int t  = threadIdx.x;
  const int wv_ = t >> 6, ln = t & 63;
  const float bq = bqkv[0];
  float4 q[4];
  float lmax = -1e30f;
  #pragma unroll
  for (int i = 0; i < 4; ++i) {
    const int n = i*1024 + t*4;
    const float* base = qpart + (size_t)bp*NNN + n;
    const float4 a = *(const float4*)(base);
    const float4 b1 = *(const float4*)(base + (size_t)NBP*NNN);
    const float4 c1 = *(const float4*)(base + (size_t)2*NBP*NNN);
    const float4 d1 = *(const float4*)(base + (size_t)3*NBP*NNN);
    q[i].x = a.x+b1.x+c1.x+d1.x + bq;
    q[i].y = a.y+b1.y+c1.y+d1.y + bq;
    q[i].z = a.z+b1.z+c1.z+d1.z + bq;
    q[i].w = a.w+b1.w+c1.w+d1.w + bq;
    lmax = fmaxf(lmax, fmaxf(fmaxf(q[i].x, q[i].y), fmaxf(q[i].z, q[i].w)));
  }
  #pragma unroll
  for (int off = 32; off; off >>= 1) lmax = fmaxf(lmax, __shfl_xor(lmax, off));
  if (ln == 0) red[wv_] = lmax;
  __syncthreads();
  const float M = fmaxf(fmaxf(red[0], red[1]), fmaxf(red[2], red[3]));
  float lsum = 0.f;
  #pragma unroll
  for (int i = 0; i < 4; ++i) {
    q[i].x = expf(q[i].x - M); q[i].y = expf(q[i].y - M);
    q[i].z = expf(q[i].z - M); q[i].w = expf(q[i].w - M);
    lsum += q[i].x + q[i].y + q[i].z + q[i].w;
  }
  #pragma unroll
  for (int off = 32; off; off >>= 1) lsum += __shfl_xor(lsum, off);
  if (ln == 0) red[4 + wv_] = lsum;
  __syncthreads();
  const float inv = 1.f / (red[4] + red[5] + red[6] + red[7]);
  #pragma unroll
  for (int i = 0; i < 4; ++i) {
    const int n = i*1024 + t*4;
    float4 o; o.x=q[i].x*inv; o.y=q[i].y*inv; o.z=q[i].z*inv; o.w=q[i].w*inv;
    *(float4*)(scores + (size_t)bp*NNN + n) = o;
  }
}

__global__ __launch_bounds__(256) void k_xs(
    const float* __restrict__ x, const float* __restrict__ scores,
    float* __restrict__ xs)
{
  __shared__ float red[4];
  const int c  = blockIdx.x;
  const int bp = blockIdx.y;
  const int b = bp >> 2, p = bp & 3;
  const float* xr = x + ((size_t)b*CC + c)*PN + (size_t)p*NNN;
  const float* sr = scores + (size_t)bp*NNN;
  float acc = 0.f;
  #pragma unroll
  for (int i = 0; i < 4; ++i) {
    const int n = i*1024 + threadIdx.x*4;
    const float4 xv = *(const float4*)(xr + n);
    const float4 sv = *(const float4*)(sr + n);
    acc += xv.x*sv.x + xv.y*sv.y + xv.z*sv.z + xv.w*sv.w;
  }
  #pragma unroll
  for (int off = 32; off; off >>= 1) acc += __shfl_xor(acc, off);
  if ((threadIdx.x & 63) == 0) red[threadIdx.x >> 6] = acc;
  __syncthreads();
  if (threadIdx.x == 0) xs[(size_t)bp*CC + c] = red[0]+red[1]+red[2]+red[3];
}

__global__ __launch_bounds__(256) void k_wcvt(
    const float* __restrict__ wqkv, const float* __restrict__ wout,
    unsigned short* __restrict__ wv, unsigned short* __restrict__ woutb)
{
  const int i = blockIdx.x*256 + threadIdx.x;
  if (i < CC*CC) wv[i] = f2bf(wqkv[385*CC + i]);
  else           woutb[i - CC*CC] = f2bf(wout[i - CC*CC]);
}

__global__ __launch_bounds__(384) void k_cv(
    const float* __restrict__ wqkv, const float* __restrict__ bqkv,
    const float* __restrict__ xs, float* __restrict__ cv)
{
  __shared__ float xsl[CC];
  const int bp = blockIdx.x;
  const int t  = threadIdx.x;
  xsl[t] = xs[(size_t)bp*CC + t];
  __syncthreads();
  float acc = bqkv[1 + t];
  const float* wk = wqkv + (size_t)(1 + t)*CC;
  #pragma unroll 8
  for (int c2 = 0; c2 < CC; ++c2) acc += wk[c2] * xsl[c2];
  cv[(size_t)bp*CC + t] = acc;
}

__device__ __forceinline__ void stage_load(
    const float* __restrict__ xb, int w, int chunk, float s[12])
{
  const int c0 = 96*chunk + 12*w;
  const float* xc = xb + (size_t)c0 * PN;
  #pragma unroll
  for (int k = 0; k < 12; ++k) s[k] = xc[(size_t)k * PN];
}

__device__ __forceinline__ void stage_write(
    char* lds, int w, int n, int chunk, const float s[12])
{
  const int swz = (n & 15) << 4;
  const int c0 = 96*chunk + 12*w;
  #pragma unroll
  for (int j = 0; j < 3; ++j) {
    u16x4 pk = { f2bf(s[4*j]), f2bf(s[4*j+1]), f2bf(s[4*j+2]), f2bf(s[4*j+3]) };
    const int byte0 = (n*768 + 2*(c0 + 4*j)) ^ swz;
    *(u16x4*)(lds + byte0) = pk;
  }
}

template<int KSN>
__device__ __forceinline__ void gemm_ks(
    const unsigned short* __restrict__ wa, const char* lds,
    int w, int g, int l15, int ks0, f32x4 acc[3][4])
{
  const unsigned short* wb = wa + (size_t)(48*w + l15)*CC + 8*g;
  s16x8 afr[2][3];
  #pragma unroll
  for (int mi = 0; mi < 3; ++mi)
    afr[0][mi] = *(const s16x8*)(wb + (size_t)(16*mi)*CC + 32*ks0);
  #pragma unroll
  for (int i = 0; i < KSN; ++i) {
    const int ks  = ks0 + i;
    const int cur = i & 1;
    if (i + 1 < KSN) {
      #pragma unroll
      for (int mi = 0; mi < 3; ++mi)
        afr[cur ^ 1][mi] = *(const s16x8*)(wb + (size_t)(16*mi)*CC + 32*(ks+1));
    }
    s16x8 bfr[4];
    #pragma unroll
    for (int nt = 0; nt < 4; ++nt) {
      const int row = 16*nt + l15;
      const int byteb = (row*768 + 64*ks + 16*g) ^ (l15 << 4);
      bfr[nt] = *(const s16x8*)(lds + byteb);
    }
    #pragma unroll
    for (int mi = 0; mi < 3; ++mi)
      #pragma unroll
      for (int nt = 0; nt < 4; ++nt)
        acc[mi][nt] = __builtin_amdgcn_mfma_f32_16x16x32_bf16(
            afr[cur][mi], bfr[nt], acc[mi][nt], 0, 0, 0);
  }
}

__global__ __launch_bounds__(512, 4) void k_main(
    const float* __restrict__ x,
    const unsigned short* __restrict__ wv,
    const unsigned short* __restrict__ woutb,
    const float* __restrict__ cv,
    const float* __restrict__ bqkv,
    const float* __restrict__ bout,
    float* __restrict__ out)
{
  __shared__ __align__(16) unsigned short lds_u16[64*384];
  char* lds = (char*)lds_u16;
  const int bid = blockIdx.x;
  const int nb  = bid & 63;
  const int bp  = bid >> 6;
  const int b = bp >> 2, p = bp & 3;
  const int n0 = nb * 64;
  const int tid  = threadIdx.x;
  const int w    = tid >> 6;
  const int lane = tid & 63;
  const int g    = lane >> 4;
  const int l15  = lane & 15;

  const float* xb = x + (size_t)b*CC*PN + (size_t)p*NNN + n0 + lane;

  float s[12];
  stage_load(xb, w, 0, s);
  stage_write(lds, w, lane, 0, s);
  stage_load(xb, w, 1, s);
  __syncthreads();

  f32x4 acc[3][4];
  #pragma unroll
  for (int i = 0; i < 3; ++i)
    #pragma unroll
    for (int j = 0; j < 4; ++j) acc[i][j] = (f32x4){0.f,0.f,0.f,0.f};

  for (int c = 0; c < 4; ++c) {
    gemm_ks<3>(wv, lds, w, g, l15, 3*c, acc);
    if (c < 3) {
      stage_write(lds, w, lane, c+1, s);
      if (c < 2) stage_load(xb, w, c+2, s);
    }
    __syncthreads();
  }

  const float* cvp = cv + (size_t)bp*CC;
  #pragma unroll
  for (int mi = 0; mi < 3; ++mi) {
    const int m0 = 48*w + 16*mi + 4*g;
    const float* bv = bqkv + 385 + m0;
    const float b0 = bv[0], b1 = bv[1], b2 = bv[2], b3 = bv[3];
    const float4 cvv = *(const float4*)(cvp + m0);
    #pragma unroll
    for (int nt = 0; nt < 4; ++nt) {
      const int row = 16*nt + l15;
      const f32x4 t = acc[mi][nt];
      u16x4 pk = { f2bf(fmaxf(t[0]+b0, 0.f)*cvv.x), f2bf(fmaxf(t[1]+b1, 0.f)*cvv.y),
                   f2bf(fmaxf(t[2]+b2, 0.f)*cvv.z), f2bf(fmaxf(t[3]+b3, 0.f)*cvv.w) };
      const int byte0 = (row*768 + 2*m0) ^ (l15 << 4);
      *(u16x4*)(lds + byte0) = pk;
    }
  }
  __syncthreads();

  #pragma unroll
  for (int i = 0; i < 3; ++i)
    #pragma unroll
    for (int j = 0; j < 4; ++j) acc[i][j] = (f32x4){0.f,0.f,0.f,0.f};

  gemm_ks<12>(woutb, lds, w, g, l15, 0, acc);

  #pragma unroll
  for (int mi = 0; mi < 3; ++mi) {
    const int m0 = 48*w + 16*mi + 4*g;
    const float4 bo = *(const float4*)(bout + m0);
    #pragma unroll
    for (int nt = 0; nt < 4; ++nt) {
      const int nn = n0 + 16*nt + l15;
      const f32x4 t = acc[mi][nt];
      float* ob = out + ((size_t)b*CC + m0)*PN + (size_t)p*NNN + nn;
      ob[0]            = t[0] + bo.x;
      ob[(size_t)PN]   = t[1] + bo.y;
      ob[2*(size_t)PN] = t[2] + bo.z;
      ob[3*(size_t)PN] = t[3] + bo.w;
    }
  }
}

// ---------------------------------------------------------------------------
extern "C" void kernel_launch(void* const* d_in, const int* in_sizes, int n_in,
                              void* d_out, int out_size, void* d_ws, size_t ws_size,
                              hipStream_t stream) {
  const float* x    = (const float*)d_in[0];
  const float* wqkv = (const float*)d_in[1];
  const float* bqkv = (const float*)d_in[2];
  const float* wout = (const float*)d_in[3];
  const float* bout = (const float*)d_in[4];
  float* out = (float*)d_out;
  char* ws = (char*)d_ws;

  // fast-path workspace layout (~100.6 MB)
  const size_t OFF_XBF = 0;                       // 2048*49152 = 100663296
  const size_t OFF_Q   = 100663296;               // 524288
  const size_t OFF_SC  = 101187584;               // 524288
  const size_t OFF_PT  = 101711872;               // 3145728
  const size_t OFF_WVT = 104857600;               // 294912
  const size_t OFF_WOT = 105152512;               // 294912
  const size_t OFF_CV  = 105447424;               // 49152
  const size_t NEED    = 105496576;

  if (ws_size >= NEED) {
    unsigned short* xbf   = (unsigned short*)(ws + OFF_XBF);
    float* q              = (float*)(ws + OFF_Q);
    float* scores         = (float*)(ws + OFF_SC);
    float* partial        = (float*)(ws + OFF_PT);
    unsigned short* wvt   = (unsigned short*)(ws + OFF_WVT);
    unsigned short* woutt = (unsigned short*)(ws + OFF_WOT);
    float* cvp            = (float*)(ws + OFF_CV);

    hipLaunchKernelGGL(k_pre,      dim3(2048), dim3(256), 0, stream, x, wqkv, xbf, q);
    hipLaunchKernelGGL(k_wcvt2,    dim3(1152), dim3(256), 0, stream, wqkv, wout, wvt, woutt);
    hipLaunchKernelGGL(k_softmax2, dim3(32),   dim3(256), 0, stream, q, bqkv, scores);
    hipLaunchKernelGGL(k_xs2,      dim3(2048), dim3(384), 0, stream, xbf, scores, partial);
    hipLaunchKernelGGL(k_cv2,      dim3(32),   dim3(384), 0, stream, partial, wqkv, bqkv, cvp);
    hipLaunchKernelGGL(k_main4,    dim3(512),  dim3(512), 0, stream, xbf, wvt, woutt, cvp, bqkv, bout, out);
  } else {
    float* scores         = (float*)(ws);
    float* qpart          = (float*)(ws + 524288);
    float* xs             = (float*)(ws + 2621440);
    unsigned short* wv    = (unsigned short*)(ws + 2719744);
    unsigned short* woutb = (unsigned short*)(ws + 3014656);
    float* cvp            = (float*)(ws + 3309568);

    hipLaunchKernelGGL(k_qpart,   dim3(512),      dim3(256), 0, stream, x, wqkv, qpart);
    hipLaunchKernelGGL(k_wcvt,    dim3(1152),     dim3(256), 0, stream, wqkv, wout, wv, woutb);
    hipLaunchKernelGGL(k_softmax, dim3(32),       dim3(256), 0, stream, qpart, bqkv, scores);
    hipLaunchKernelGGL(k_xs,      dim3(CC, NBP),  dim3(256), 0, stream, x, scores, xs);
    hipLaunchKernelGGL(k_cv,      dim3(NBP),      dim3(384), 0, stream, wqkv, bqkv, xs, cvp);
    hipLaunchKernelGGL(k_main,    dim3(2048),     dim3(512), 0, stream, x, wv, woutb, cvp, bqkv, bout, out);
  }
}

// Round 10
// 241.366 us; speedup vs baseline: 2.1767x; 2.1767x over previous
//
#include <hip/hip_runtime.h>
#include <hip/hip_bf16.h>
#include <stdint.h>

// Problem constants
#define CC   384          // EMBED_DIM
#define BB   8
#define PP   4
#define NNN  4096
#define NBP  32           // B*P slices
#define PN   (PP*NNN)     // stride between channels in x/out (=16384 floats)

#define AS1 __attribute__((address_space(1)))
#define AS3 __attribute__((address_space(3)))

typedef float  f32x4 __attribute__((ext_vector_type(4)));
typedef short  s16x8 __attribute__((ext_vector_type(8)));
typedef unsigned short u16x4 __attribute__((ext_vector_type(4)));

__device__ __forceinline__ unsigned short f2bf(float f) {
  unsigned int u = __float_as_uint(f);
  u += 0x7fffu + ((u >> 16) & 1u);
  return (unsigned short)(u >> 16);
}
__device__ __forceinline__ float bf2f(unsigned short u) {
  return __uint_as_float(((unsigned int)u) << 16);
}

// Image swizzle: nonlinear in low row bits so both 16-consecutive-row reads
// (consumer) and stride-4-row writes (producer) spread over 8 bank groups.
__device__ __forceinline__ int swz16(int r) {
  return ((r ^ (r >> 2)) & 15) << 4;
}

// async global->LDS, 16B per lane. g is per-lane, l is wave-uniform base.
__device__ __forceinline__ void stage16(const char* g, char* l_uniform, int lane) {
#if defined(__has_builtin) && __has_builtin(__builtin_amdgcn_global_load_lds)
  __builtin_amdgcn_global_load_lds((const AS1 unsigned int*)g,
                                   (AS3 unsigned int*)l_uniform, 16, 0, 0);
#else
  *(int4*)(l_uniform + lane*16) = *(const int4*)g;
#endif
}

// ===========================================================================
// ============================ FAST PATH ====================================
// ===========================================================================

// K_PRE: per (bp, 64-n tile): transpose x -> swz16-swizzled bf16 LDS image
// (row r = local n, 768B/row), write 48KB to xbf[bid]; fold q-partials
// (q = w_q . x, fp32) in the same pass. grid=2048, block=256.
__global__ __launch_bounds__(256) void k_pre(
    const float* __restrict__ x, const float* __restrict__ wqkv,
    unsigned short* __restrict__ xbf, float* __restrict__ q)
{
  __shared__ __align__(16) unsigned short tr[24576];   // 48KB image
  __shared__ float4 qw[64];
  char* trb = (char*)tr;
  const int bid = blockIdx.x;
  const int bp = bid >> 6, nt = bid & 63;
  const int b = bp >> 2, p = bp & 3;
  const int n0 = nt * 64;
  const int t  = threadIdx.x;
  const int wv_ = t >> 6, lane = t & 63;
  const int cg = t >> 4, nv = t & 15;     // c-pair group 0..15, n-subvec 0..15
  const int r0 = 4 * nv;
  const float* xb = x + (size_t)b*CC*PN + (size_t)p*NNN + n0 + r0;
  const int s0 = swz16(r0+0), s1 = swz16(r0+1), s2 = swz16(r0+2), s3 = swz16(r0+3);

  float4 qa = {0.f, 0.f, 0.f, 0.f};
  #pragma unroll 3
  for (int it = 0; it < 12; ++it) {
    const int c0 = 32*it + 2*cg;
    const float4 x0 = *(const float4*)(xb + (size_t)c0*PN);
    const float4 x1 = *(const float4*)(xb + (size_t)(c0+1)*PN);
    const float w0 = wqkv[c0], w1 = wqkv[c0+1];
    qa.x += w0*x0.x + w1*x1.x;
    qa.y += w0*x0.y + w1*x1.y;
    qa.z += w0*x0.z + w1*x1.z;
    qa.w += w0*x0.w + w1*x1.w;
    const unsigned int p0 = (unsigned)f2bf(x0.x) | ((unsigned)f2bf(x1.x) << 16);
    const unsigned int p1 = (unsigned)f2bf(x0.y) | ((unsigned)f2bf(x1.y) << 16);
    const unsigned int p2 = (unsigned)f2bf(x0.z) | ((unsigned)f2bf(x1.z) << 16);
    const unsigned int p3 = (unsigned)f2bf(x0.w) | ((unsigned)f2bf(x1.w) << 16);
    const int cb = 2*c0;
    *(unsigned int*)(trb + (((r0+0)*768 + cb) ^ s0)) = p0;
    *(unsigned int*)(trb + (((r0+1)*768 + cb) ^ s1)) = p1;
    *(unsigned int*)(trb + (((r0+2)*768 + cb) ^ s2)) = p2;
    *(unsigned int*)(trb + (((r0+3)*768 + cb) ^ s3)) = p3;
  }
  // reduce q over the 16 c-groups: lanes differ in bits 4,5 within wave
  qa.x += __shfl_xor(qa.x, 16); qa.y += __shfl_xor(qa.y, 16);
  qa.z += __shfl_xor(qa.z, 16); qa.w += __shfl_xor(qa.w, 16);
  qa.x += __shfl_xor(qa.x, 32); qa.y += __shfl_xor(qa.y, 32);
  qa.z += __shfl_xor(qa.z, 32); qa.w += __shfl_xor(qa.w, 32);
  if (lane < 16) qw[wv_*16 + lane] = qa;
  __syncthreads();
  // copy image out (coalesced 16B)
  const int4* trs = (const int4*)tr;
  int4* dst = (int4*)(xbf + (size_t)bid * 24576);
  #pragma unroll
  for (int j = 0; j < 12; ++j) dst[j*256 + t] = trs[j*256 + t];
  if (t < 16) {
    float4 a0 = qw[t], a1 = qw[16+t], a2 = qw[32+t], a3 = qw[48+t];
    float4 o; o.x = a0.x+a1.x+a2.x+a3.x; o.y = a0.y+a1.y+a2.y+a3.y;
    o.z = a0.z+a1.z+a2.z+a3.z; o.w = a0.w+a1.w+a2.w+a3.w;
    *(float4*)(q + (size_t)bp*NNN + n0 + 4*t) = o;
  }
}

// K_WCVT2: W_v & W_out -> bf16, fragment-major tiling:
// idx(mf,ks,l15,g,j) = (mf*12+ks)*512 + l15*32 + g*8 + j ; row=16mf+l15, col=32ks+8g+j
__global__ __launch_bounds__(256) void k_wcvt2(
    const float* __restrict__ wqkv, const float* __restrict__ wout,
    unsigned short* __restrict__ wvt, unsigned short* __restrict__ woutt)
{
  const int i = blockIdx.x*256 + threadIdx.x;   // 0..294911
  const int e = (i < CC*CC) ? i : i - CC*CC;
  const int j   = e & 7;
  const int g   = (e >> 3) & 3;
  const int l15 = (e >> 5) & 15;
  const int rem = e >> 9;          // 0..287
  const int ks  = rem % 12;
  const int mf  = rem / 12;
  const int row = 16*mf + l15;
  const int col = 32*ks + 8*g + j;
  if (i < CC*CC) wvt[e]          = f2bf(wqkv[(size_t)(385 + row)*CC + col]);
  else           woutt[e]        = f2bf(wout[(size_t)row*CC + col]);
}

// K_SOFTMAX2: softmax over n per bp. grid=32, block=256.
__global__ __launch_bounds__(256) void k_softmax2(
    const float* __restrict__ q, const float* __restrict__ bqkv,
    float* __restrict__ scores)
{
  __shared__ float red[8];
  const int bp = blockIdx.x;
  const int t  = threadIdx.x;
  const int wv_ = t >> 6, ln = t & 63;
  const float bq = bqkv[0];
  float4 qv[4];
  float lmax = -1e30f;
  #pragma unroll
  for (int i = 0; i < 4; ++i) {
    const int n = i*1024 + t*4;
    float4 a = *(const float4*)(q + (size_t)bp*NNN + n);
    qv[i].x = a.x + bq; qv[i].y = a.y + bq; qv[i].z = a.z + bq; qv[i].w = a.w + bq;
    lmax = fmaxf(lmax, fmaxf(fmaxf(qv[i].x, qv[i].y), fmaxf(qv[i].z, qv[i].w)));
  }
  #pragma unroll
  for (int off = 32; off; off >>= 1) lmax = fmaxf(lmax, __shfl_xor(lmax, off));
  if (ln == 0) red[wv_] = lmax;
  __syncthreads();
  const float M = fmaxf(fmaxf(red[0], red[1]), fmaxf(red[2], red[3]));
  float lsum = 0.f;
  #pragma unroll
  for (int i = 0; i < 4; ++i) {
    qv[i].x = expf(qv[i].x - M); qv[i].y = expf(qv[i].y - M);
    qv[i].z = expf(qv[i].z - M); qv[i].w = expf(qv[i].w - M);
    lsum += qv[i].x + qv[i].y + qv[i].z + qv[i].w;
  }
  #pragma unroll
  for (int off = 32; off; off >>= 1) lsum += __shfl_xor(lsum, off);
  if (ln == 0) red[4 + wv_] = lsum;
  __syncthreads();
  const float inv = 1.f / (red[4] + red[5] + red[6] + red[7]);
  #pragma unroll
  for (int i = 0; i < 4; ++i) {
    const int n = i*1024 + t*4;
    float4 o; o.x=qv[i].x*inv; o.y=qv[i].y*inv; o.z=qv[i].z*inv; o.w=qv[i].w*inv;
    *(float4*)(scores + (size_t)bp*NNN + n) = o;
  }
}

// K_XS2: per (bp, tile): partial[bid][c] = sum_r xbf(r,c) * s[r]. grid=2048, block=384.
__global__ __launch_bounds__(384) void k_xs2(
    const unsigned short* __restrict__ xbf, const float* __restrict__ scores,
    float* __restrict__ partial)
{
  __shared__ __align__(16) char lds[49152];
  __shared__ float sl[64];
  const int bid = blockIdx.x;
  const int bp = bid >> 6, nt = bid & 63;
  const int t = threadIdx.x;
  const int w6 = t >> 6, lane = t & 63;
  const char* gsrc = (const char*)xbf + (size_t)bid * 49152;
  #pragma unroll
  for (int r = 0; r < 8; ++r) {
    const int loff = (r*6 + w6) * 1024;
    stage16(gsrc + loff + lane*16, lds + loff, lane);
  }
  if (t < 64) sl[t] = scores[(size_t)bp*NNN + nt*64 + t];
  __syncthreads();
  float acc = 0.f;
  #pragma unroll 8
  for (int r = 0; r < 64; ++r) {
    const unsigned short uv = *(const unsigned short*)(lds + ((r*768 + 2*t) ^ swz16(r)));
    acc += bf2f(uv) * sl[r];
  }
  partial[(size_t)bid*CC + t] = acc;
}

// K_CV2: xs[c] = sum_nt partial ; cv[bp][c] = b_k[c] + W_k[c].xs. grid=32, block=384.
__global__ __launch_bounds__(384) void k_cv2(
    const float* __restrict__ partial, const float* __restrict__ wqkv,
    const float* __restrict__ bqkv, float* __restrict__ cv)
{
  __shared__ float xsl[CC];
  const int bp = blockIdx.x;
  const int t  = threadIdx.x;
  float s = 0.f;
  #pragma unroll 8
  for (int nt = 0; nt < 64; ++nt) s += partial[((size_t)bp*64 + nt)*CC + t];
  xsl[t] = s;
  __syncthreads();
  float acc = bqkv[1 + t];
  const float* wk = wqkv + (size_t)(1 + t)*CC;
  #pragma unroll 8
  for (int c2 = 0; c2 < CC; ++c2) acc += wk[c2] * xsl[c2];
  cv[(size_t)bp*CC + t] = acc;
}

// K_MAIN2: fused double GEMM (best-known config, R5 structure + swz16).
// 2048 blocks x 512 thr, 1 tile/block. x image via global_load_lds; A from
// fragment-major W (L2-resident with 2048 concurrent readers) 3-deep rolling
// prefetch; epi2 = col-split LDS transpose WITH fill swizzle + NT stores.
__device__ __forceinline__ void gemm_t(
    const unsigned short* __restrict__ wt, const char* lds,
    int w, int g, int l15, f32x4 acc[3][4])
{
  // per-wave fragment base: mf = 3w + mi ; A(mi,ks) at base + (mi*12+ks)*512
  const unsigned short* base = wt + (size_t)(3*w)*12*512 + l15*32 + g*8;
  s16x8 a[3][3];   // [slot = ks%3][mi]
  #pragma unroll
  for (int pf = 0; pf < 3; ++pf)
    #pragma unroll
    for (int mi = 0; mi < 3; ++mi)
      a[pf][mi] = *(const s16x8*)(base + ((size_t)mi*12 + pf)*512);
  #pragma unroll
  for (int ks = 0; ks < 12; ++ks) {
    const int slot = ks % 3;
    s16x8 bfr[4];
    #pragma unroll
    for (int nt = 0; nt < 4; ++nt) {
      const int row = 16*nt + l15;
      const int byteb = (row*768 + 64*ks + 16*g) ^ swz16(row);
      bfr[nt] = *(const s16x8*)(lds + byteb);
    }
    #pragma unroll
    for (int mi = 0; mi < 3; ++mi)
      #pragma unroll
      for (int nt = 0; nt < 4; ++nt)
        acc[mi][nt] = __builtin_amdgcn_mfma_f32_16x16x32_bf16(
            a[slot][mi], bfr[nt], acc[mi][nt], 0, 0, 0);
    if (ks + 3 < 12) {
      #pragma unroll
      for (int mi = 0; mi < 3; ++mi)
        a[slot][mi] = *(const s16x8*)(base + ((size_t)mi*12 + ks + 3)*512);
    }
  }
}

__global__ __launch_bounds__(512, 4) void k_main2(
    const unsigned short* __restrict__ xbf,
    const unsigned short* __restrict__ wvt,
    const unsigned short* __restrict__ woutt,
    const float* __restrict__ cv,
    const float* __restrict__ bqkv,
    const float* __restrict__ bout,
    float* __restrict__ out)
{
  __shared__ __align__(16) char lds[49152];
  const int bid = blockIdx.x;
  const int nb  = bid & 63;
  const int bp  = bid >> 6;
  const int b = bp >> 2, p = bp & 3;
  const int n0 = nb * 64;
  const int tid  = threadIdx.x;
  const int w    = tid >> 6;        // 0..7
  const int lane = tid & 63;
  const int g    = lane >> 4;
  const int l15  = lane & 15;

  // ---- stage 48KB x image (async, contiguous)
  {
    const char* gsrc = (const char*)xbf + (size_t)bid * 49152;
    #pragma unroll
    for (int r = 0; r < 6; ++r) {
      const int loff = (r*8 + w) * 1024;
      stage16(gsrc + loff + lane*16, lds + loff, lane);
    }
  }
  __syncthreads();

  f32x4 acc[3][4];
  #pragma unroll
  for (int i = 0; i < 3; ++i)
    #pragma unroll
    for (int j = 0; j < 4; ++j) acc[i][j] = (f32x4){0.f,0.f,0.f,0.f};

  // ---- GEMM1: v = W_v @ x
  gemm_t(wvt, lds, w, g, l15, acc);
  __syncthreads();

  // ---- epi1: relu(v + b_v) * cv -> bf16 back into same LDS buffer
  const float* cvp = cv + (size_t)bp*CC;
  #pragma unroll
  for (int mi = 0; mi < 3; ++mi) {
    const int m0 = 48*w + 16*mi + 4*g;
    const float* bv = bqkv + 385 + m0;
    const float b0 = bv[0], b1 = bv[1], b2 = bv[2], b3 = bv[3];
    const float4 cvv = *(const float4*)(cvp + m0);
    #pragma unroll
    for (int nt = 0; nt < 4; ++nt) {
      const int row = 16*nt + l15;
      const f32x4 t = acc[mi][nt];
      u16x4 pk = { f2bf(fmaxf(t[0]+b0, 0.f)*cvv.x), f2bf(fmaxf(t[1]+b1, 0.f)*cvv.y),
                   f2bf(fmaxf(t[2]+b2, 0.f)*cvv.z), f2bf(fmaxf(t[3]+b3, 0.f)*cvv.w) };
      const int byte0 = (row*768 + 2*m0) ^ swz16(row);
      *(u16x4*)(lds + byte0) = pk;
    }
  }
  __syncthreads();

  #pragma unroll
  for (int i = 0; i < 3; ++i)
    #pragma unroll
    for (int j = 0; j < 4; ++j) acc[i][j] = (f32x4){0.f,0.f,0.f,0.f};

  // ---- GEMM2: out = W_out @ v
  gemm_t(woutt, lds, w, g, l15, acc);

  // ---- epi2: +b_out, col-split LDS transpose ([384][32] fp32) with
  // fill swizzle col ^= g<<3 (2 lanes/bank = free), NT 128B drains.
  float* fl = (float*)lds;
  float* outb = out + (size_t)b*CC*PN + (size_t)p*NNN + n0;
  #pragma unroll
  for (int half = 0; half < 2; ++half) {
    __syncthreads();   // GEMM2 reads of LDS done / prev half drained
    #pragma unroll
    for (int mi = 0; mi < 3; ++mi) {
      const int m0 = 48*w + 16*mi + 4*g;
      const float4 bo = *(const float4*)(bout + m0);
      const int cswz = g << 3;     // = ((m0>>2)&3) << 3
      #pragma unroll
      for (int nt2 = 0; nt2 < 2; ++nt2) {
        const f32x4 t = acc[mi][2*half + nt2];
        const int colh = (16*nt2 + l15) ^ cswz;
        fl[(m0+0)*32 + colh] = t[0] + bo.x;
        fl[(m0+1)*32 + colh] = t[1] + bo.y;
        fl[(m0+2)*32 + colh] = t[2] + bo.z;
        fl[(m0+3)*32 + colh] = t[3] + bo.w;
      }
    }
    __syncthreads();
    // drain 384x32 fp32: 512 threads x float4 x 6 passes; 8 lanes = 128B
    #pragma unroll
    for (int ps = 0; ps < 6; ++ps) {
      const int idx = ps*512 + tid;              // 0..3071 float4 slots
      const int row = idx >> 3;
      const int nq  = idx & 7;
      const int qb  = (nq*4) ^ (((row >> 2) & 3) << 3);
      const f32x4 v = *(const f32x4*)(fl + row*32 + qb);
      __builtin_nontemporal_store(v, (f32x4*)(outb + (size_t)row*PN + 32*half + nq*4));
    }
  }
}

// ===========================================================================
// ========================= FALLBACK PATH (R3) ==============================
// ===========================================================================

__global__ __launch_bounds__(256) void k_qpart(
    const float* __restrict__ x, const float* __restrict__ wqkv,
    float* __restrict__ qpart)
{
  const int bid = blockIdx.x;
  const int seg = bid & 3;
  const int nc  = (bid >> 2) & 3;
  const int bp  = bid >> 4;
  const int b = bp >> 2, p = bp & 3;
  const int n = nc * 1024 + threadIdx.x * 4;
  const float* xb = x + (size_t)b*CC*PN + (size_t)p*NNN + n;
  float ax = 0.f, ay = 0.f, az = 0.f, aw = 0.f;
  const int c0 = seg * 96;
  #pragma unroll 8
  for (int c = c0; c < c0 + 96; ++c) {
    const float w = wqkv[c];
    const float4 xv = *(const float4*)(xb + (size_t)c*PN);
    ax += w*xv.x; ay += w*xv.y; az += w*xv.z; aw += w*xv.w;
  }
  float4 o; o.x=ax; o.y=ay; o.z=az; o.w=aw;
  *(float4*)(qpart + (size_t)(seg*NBP + bp)*NNN + n) = o;
}

__global__ __launch_bounds__(256) void k_softmax(
    const float* __restrict__ qpart, const float* __restrict__ bqkv,
    float* __restrict__ scores)
{
  __shared__ float red[8];
  const int bp = blockIdx.x;
  const int t  = threadIdx.x;
  const int wv_ = t >> 6, ln = t & 63;
  const float bq = bqkv[0];
  float4 q[4];
  float lmax = -1e30f;
  #pragma unroll
  for (int i = 0; i < 4; ++i) {
    const int n = i*1024 + t*4;
    const float* base = qpart + (size_t)bp*NNN + n;
    const float4 a = *(const float4*)(base);
    const float4 b1 = *(const float4*)(base + (size_t)NBP*NNN);
    const float4 c1 = *(const float4*)(base + (size_t)2*NBP*NNN);
    const float4 d1 = *(const float4*)(base + (size_t)3*NBP*NNN);
    q[i].x = a.x+b1.x+c1.x+d1.x + bq;
    q[i].y = a.y+b1.y+c1.y+d1.y + bq;
    q[i].z = a.z+b1.z+c1.z+d1.z + bq;
    q[i].w = a.w+b1.w+c1.w+d1.w + bq;
    lmax = fmaxf(lmax, fmaxf(fmaxf(q[i].x, q[i].y), fmaxf(q[i].z, q[i].w)));
  }
  #pragma unroll
  for (int off = 32; off; off >>= 1) lmax = fmaxf(lmax, __shfl_xor(lmax, off));
  if (ln == 0) red[wv_] = lmax;
  __syncthreads();
  const float M = fmaxf(fmaxf(red[0], red[1]), fmaxf(red[2], red[3]));
  float lsum = 0.f;
  #pragma unroll
  for (int i = 0; i < 4; ++i) {
    q[i].x = expf(q[i].x - M); q[i].y = expf(q[i].y - M);
    q[i].z = expf(q[i].z - M); q[i].w = expf(q[i].w - M);
    lsum += q[i].x + q[i].y + q[i].z + q[i].w;
  }
  #pragma unroll
  for (int off = 32; off; off >>= 1) lsum += __shfl_xor(lsum, off);
  if (ln == 0) red[4 + wv_] = lsum;
  __syncthreads();
  const float inv = 1.f / (red[4] + red[5] + red[6] + red[7]);
  #pragma unroll
  for (int i = 0; i < 4; ++i) {
    const int n = i*1024 + t*4;
    float4 o; o.x=q[i].x*inv; o.y=q[i].y*inv; o.z=q[i].z*inv; o.w=q[i].w*inv;
    *(float4*)(scores + (size_t)bp*NNN + n) = o;
  }
}

__global__ __launch_bounds__(256) void k_xs(
    const float* __restrict__ x, const float* __restrict__ scores,
    float* __restrict__ xs)
{
  __shared__ float red[4];
  const int c  = blockIdx.x;
  const int bp = blockIdx.y;
  const int b = bp >> 2, p = bp & 3;
  const float* xr = x + ((size_t)b*CC + c)*PN + (size_t)p*NNN;
  const float* sr = scores + (size_t)bp*NNN;
  float acc = 0.f;
  #pragma unroll
  for (int i = 0; i < 4; ++i) {
    const int n = i*1024 + threadIdx.x*4;
    const float4 xv = *(const float4*)(xr + n);
    const float4 sv = *(const float4*)(sr + n);
    acc += xv.x*sv.x + xv.y*sv.y + xv.z*sv.z + xv.w*sv.w;
  }
  #pragma unroll
  for (int off = 32; off; off >>= 1) acc += __shfl_xor(acc, off);
  if ((threadIdx.x & 63) == 0) red[threadIdx.x >> 6] = acc;
  __syncthreads();
  if (threadIdx.x == 0) xs[(size_t)bp*CC + c] = red[0]+red[1]+red[2]+red[3];
}

__global__ __launch_bounds__(256) void k_wcvt(
    const float* __restrict__ wqkv, const float* __restrict__ wout,
    unsigned short* __restrict__ wv, unsigned short* __restrict__ woutb)
{
  const int i = blockIdx.x*256 + threadIdx.x;
  if (i < CC*CC) wv[i] = f2bf(wqkv[385*CC + i]);
  else           woutb[i - CC*CC] = f2bf(wout[i - CC*CC]);
}

__global__ __launch_bounds__(384) void k_cv(
    const float* __restrict__ wqkv, const float* __restrict__ bqkv,
    const float* __restrict__ xs, float* __restrict__ cv)
{
  __shared__ float xsl[CC];
  const int bp = blockIdx.x;
  const int t  = threadIdx.x;
  xsl[t] = xs[(size_t)bp*CC + t];
  __syncthreads();
  float acc = bqkv[1 + t];
  const float* wk = wqkv + (size_t)(1 + t)*CC;
  #pragma unroll 8
  for (int c2 = 0; c2 < CC; ++c2) acc += wk[c2] * xsl[c2];
  cv[(size_t)bp*CC + t] = acc;
}

__device__ __forceinline__ void stage_load(
    const float* __restrict__ xb, int w, int chunk, float s[12])
{
  const int c0 = 96*chunk + 12*w;
  const float* xc = xb + (size_t)c0 * PN;
  #pragma unroll
  for (int k = 0; k < 12; ++k) s[k] = xc[(size_t)k * PN];
}

__device__ __forceinline__ void stage_write(
    char* lds, int w, int n, int chunk, const float s[12])
{
  const int swz = (n & 15) << 4;
  const int c0 = 96*chunk + 12*w;
  #pragma unroll
  for (int j = 0; j < 3; ++j) {
    u16x4 pk = { f2bf(s[4*j]), f2bf(s[4*j+1]), f2bf(s[4*j+2]), f2bf(s[4*j+3]) };
    const int byte0 = (n*768 + 2*(c0 + 4*j)) ^ swz;
    *(u16x4*)(lds + byte0) = pk;
  }
}

template<int KSN>
__device__ __forceinline__ void gemm_ks(
    const unsigned short* __restrict__ wa, const char* lds,
    int w, int g, int l15, int ks0, f32x4 acc[3][4])
{
  const unsigned short* wb = wa + (size_t)(48*w + l15)*CC + 8*g;
  s16x8 afr[2][3];
  #pragma unroll
  for (int mi = 0; mi < 3; ++mi)
    afr[0][mi] = *(const s16x8*)(wb + (size_t)(16*mi)*CC + 32*ks0);
  #pragma unroll
  for (int i = 0; i < KSN; ++i) {
    const int ks  = ks0 + i;
    const int cur = i & 1;
    if (i + 1 < KSN) {
      #pragma unroll
      for (int mi = 0; mi < 3; ++mi)
        afr[cur ^ 1][mi] = *(const s16x8*)(wb + (size_t)(16*mi)*CC + 32*(ks+1));
    }
    s16x8 bfr[4];
    #pragma unroll
    for (int nt = 0; nt < 4; ++nt) {
      const int row = 16*nt + l15;
      const int byteb = (row*768 + 64*ks + 16*g) ^ (l15 << 4);
      bfr[nt] = *(const s16x8*)(lds + byteb);
    }
    #pragma unroll
    for (int mi = 0; mi < 3; ++mi)
      #pragma unroll
      for (int nt = 0; nt < 4; ++nt)
        acc[mi][nt] = __builtin_amdgcn_mfma_f32_16x16x32_bf16(
            afr[cur][mi], bfr[nt], acc[mi][nt], 0, 0, 0);
  }
}

__global__ __launch_bounds__(512, 4) void k_main(
    const float* __restrict__ x,
    const unsigned short* __restrict__ wv,
    const unsigned short* __restrict__ woutb,
    const float* __restrict__ cv,
    const float* __restrict__ bqkv,
    const float* __restrict__ bout,
    float* __restrict__ out)
{
  __shared__ __align__(16) unsigned short lds_u16[64*384];
  char* lds = (char*)lds_u16;
  const int bid = blockIdx.x;
  const int nb  = bid & 63;
  const int bp  = bid >> 6;
  const int b = bp >> 2, p = bp & 3;
  const int n0 = nb * 64;
  const int tid  = threadIdx.x;
  const int w    = tid >> 6;
  const int lane = tid & 63;
  const int g    = lane >> 4;
  const int l15  = lane & 15;

  const float* xb = x + (size_t)b*CC*PN + (size_t)p*NNN + n0 + lane;

  float s[12];
  stage_load(xb, w, 0, s);
  stage_write(lds, w, lane, 0, s);
  stage_load(xb, w, 1, s);
  __syncthreads();

  f32x4 acc[3][4];
  #pragma unroll
  for (int i = 0; i < 3; ++i)
    #pragma unroll
    for (int j = 0; j < 4; ++j) acc[i][j] = (f32x4){0.f,0.f,0.f,0.f};

  for (int c = 0; c < 4; ++c) {
    gemm_ks<3>(wv, lds, w, g, l15, 3*c, acc);
    if (c < 3) {
      stage_write(lds, w, lane, c+1, s);
      if (c < 2) stage_load(xb, w, c+2, s);
    }
    __syncthreads();
  }

  const float* cvp = cv + (size_t)bp*CC;
  #pragma unroll
  for (int mi = 0; mi < 3; ++mi) {
    const int m0 = 48*w + 16*mi + 4*g;
    const float* bv = bqkv + 385 + m0;
    const float b0 = bv[0], b1 = bv[1], b2 = bv[2], b3 = bv[3];
    const float4 cvv = *(const float4*)(cvp + m0);
    #pragma unroll
    for (int nt = 0; nt < 4; ++nt) {
      const int row = 16*nt + l15;
      const f32x4 t = acc[mi][nt];
      u16x4 pk = { f2bf(fmaxf(t[0]+b0, 0.f)*cvv.x), f2bf(fmaxf(t[1]+b1, 0.f)*cvv.y),
                   f2bf(fmaxf(t[2]+b2, 0.f)*cvv.z), f2bf(fmaxf(t[3]+b3, 0.f)*cvv.w) };
      const int byte0 = (row*768 + 2*m0) ^ (l15 << 4);
      *(u16x4*)(lds + byte0) = pk;
    }
  }
  __syncthreads();

  #pragma unroll
  for (int i = 0; i < 3; ++i)
    #pragma unroll
    for (int j = 0; j < 4; ++j) acc[i][j] = (f32x4){0.f,0.f,0.f,0.f};

  gemm_ks<12>(woutb, lds, w, g, l15, 0, acc);

  #pragma unroll
  for (int mi = 0; mi < 3; ++mi) {
    const int m0 = 48*w + 16*mi + 4*g;
    const float4 bo = *(const float4*)(bout + m0);
    #pragma unroll
    for (int nt = 0; nt < 4; ++nt) {
      const int nn = n0 + 16*nt + l15;
      const f32x4 t = acc[mi][nt];
      float* ob = out + ((size_t)b*CC + m0)*PN + (size_t)p*NNN + nn;
      ob[0]            = t[0] + bo.x;
      ob[(size_t)PN]   = t[1] + bo.y;
      ob[2*(size_t)PN] = t[2] + bo.z;
      ob[3*(size_t)PN] = t[3] + bo.w;
    }
  }
}

// ---------------------------------------------------------------------------
extern "C" void kernel_launch(void* const* d_in, const int* in_sizes, int n_in,
                              void* d_out, int out_size, void* d_ws, size_t ws_size,
                              hipStream_t stream) {
  const float* x    = (const float*)d_in[0];
  const float* wqkv = (const float*)d_in[1];
  const float* bqkv = (const float*)d_in[2];
  const float* wout = (const float*)d_in[3];
  const float* bout = (const float*)d_in[4];
  float* out = (float*)d_out;
  char* ws = (char*)d_ws;

  // fast-path workspace layout (~100.6 MB)
  const size_t OFF_XBF = 0;                       // 2048*49152 = 100663296
  const size_t OFF_Q   = 100663296;               // 524288
  const size_t OFF_SC  = 101187584;               // 524288
  const size_t OFF_PT  = 101711872;               // 3145728
  const size_t OFF_WVT = 104857600;               // 294912
  const size_t OFF_WOT = 105152512;               // 294912
  const size_t OFF_CV  = 105447424;               // 49152
  const size_t NEED    = 105496576;

  if (ws_size >= NEED) {
    unsigned short* xbf   = (unsigned short*)(ws + OFF_XBF);
    float* q              = (float*)(ws + OFF_Q);
    float* scores         = (float*)(ws + OFF_SC);
    float* partial        = (float*)(ws + OFF_PT);
    unsigned short* wvt   = (unsigned short*)(ws + OFF_WVT);
    unsigned short* woutt = (unsigned short*)(ws + OFF_WOT);
    float* cvp            = (float*)(ws + OFF_CV);

    hipLaunchKernelGGL(k_pre,      dim3(2048), dim3(256), 0, stream, x, wqkv, xbf, q);
    hipLaunchKernelGGL(k_wcvt2,    dim3(1152), dim3(256), 0, stream, wqkv, wout, wvt, woutt);
    hipLaunchKernelGGL(k_softmax2, dim3(32),   dim3(256), 0, stream, q, bqkv, scores);
    hipLaunchKernelGGL(k_xs2,      dim3(2048), dim3(384), 0, stream, xbf, scores, partial);
    hipLaunchKernelGGL(k_cv2,      dim3(32),   dim3(384), 0, stream, partial, wqkv, bqkv, cvp);
    hipLaunchKernelGGL(k_main2,    dim3(2048), dim3(512), 0, stream, xbf, wvt, woutt, cvp, bqkv, bout, out);
  } else {
    float* scores         = (float*)(ws);
    float* qpart          = (float*)(ws + 524288);
    float* xs             = (float*)(ws + 2621440);
    unsigned short* wv    = (unsigned short*)(ws + 2719744);
    unsigned short* woutb = (unsigned short*)(ws + 3014656);
    float* cvp            = (float*)(ws + 3309568);

    hipLaunchKernelGGL(k_qpart,   dim3(512),      dim3(256), 0, stream, x, wqkv, qpart);
    hipLaunchKernelGGL(k_wcvt,    dim3(1152),     dim3(256), 0, stream, wqkv, wout, wv, woutb);
    hipLaunchKernelGGL(k_softmax, dim3(32),       dim3(256), 0, stream, qpart, bqkv, scores);
    hipLaunchKernelGGL(k_xs,      dim3(CC, NBP),  dim3(256), 0, stream, x, scores, xs);
    hipLaunchKernelGGL(k_cv,      dim3(NBP),      dim3(384), 0, stream, wqkv, bqkv, xs, cvp);
    hipLaunchKernelGGL(k_main,    dim3(2048),     dim3(512), 0, stream, x, wv, woutb, cvp, bqkv, bout, out);
  }
}

// Round 11
// 233.267 us; speedup vs baseline: 2.2523x; 1.0347x over previous
//
#include <hip/hip_runtime.h>
#include <hip/hip_bf16.h>
#include <stdint.h>

// Problem constants
#define CC   384          // EMBED_DIM
#define BB   8
#define PP   4
#define NNN  4096
#define NBP  32           // B*P slices
#define PN   (PP*NNN)     // stride between channels in x/out (=16384 floats)

#define AS1 __attribute__((address_space(1)))
#define AS3 __attribute__((address_space(3)))

typedef float  f32x4 __attribute__((ext_vector_type(4)));
typedef short  s16x8 __attribute__((ext_vector_type(8)));
typedef unsigned short u16x4 __attribute__((ext_vector_type(4)));

__device__ __forceinline__ unsigned short f2bf(float f) {
  unsigned int u = __float_as_uint(f);
  u += 0x7fffu + ((u >> 16) & 1u);
  return (unsigned short)(u >> 16);
}
__device__ __forceinline__ float bf2f(unsigned short u) {
  return __uint_as_float(((unsigned int)u) << 16);
}

// Image swizzle: nonlinear in low row bits so both 16-consecutive-row reads
// (consumer) and stride-4-row writes (producer) spread over 8 bank groups.
__device__ __forceinline__ int swz16(int r) {
  return ((r ^ (r >> 2)) & 15) << 4;
}

// async global->LDS, 16B per lane. g is per-lane, l is wave-uniform base.
__device__ __forceinline__ void stage16(const char* g, char* l_uniform, int lane) {
#if defined(__has_builtin) && __has_builtin(__builtin_amdgcn_global_load_lds)
  __builtin_amdgcn_global_load_lds((const AS1 unsigned int*)g,
                                   (AS3 unsigned int*)l_uniform, 16, 0, 0);
#else
  *(int4*)(l_uniform + lane*16) = *(const int4*)g;
#endif
}

// ===========================================================================
// ============================ FAST PATH ====================================
// ===========================================================================

// K_PRE: per (bp, 64-n tile): transpose x -> swz16-swizzled bf16 LDS image
// (row r = local n, 768B/row), write 48KB to xbf[bid]; fold q-partials
// (q = w_q . x, fp32) in the same pass. grid=2048, block=256.
__global__ __launch_bounds__(256) void k_pre(
    const float* __restrict__ x, const float* __restrict__ wqkv,
    unsigned short* __restrict__ xbf, float* __restrict__ q)
{
  __shared__ __align__(16) unsigned short tr[24576];   // 48KB image
  __shared__ float4 qw[64];
  char* trb = (char*)tr;
  const int bid = blockIdx.x;
  const int bp = bid >> 6, nt = bid & 63;
  const int b = bp >> 2, p = bp & 3;
  const int n0 = nt * 64;
  const int t  = threadIdx.x;
  const int wv_ = t >> 6, lane = t & 63;
  const int cg = t >> 4, nv = t & 15;     // c-pair group 0..15, n-subvec 0..15
  const int r0 = 4 * nv;
  const float* xb = x + (size_t)b*CC*PN + (size_t)p*NNN + n0 + r0;
  const int s0 = swz16(r0+0), s1 = swz16(r0+1), s2 = swz16(r0+2), s3 = swz16(r0+3);

  float4 qa = {0.f, 0.f, 0.f, 0.f};
  #pragma unroll 3
  for (int it = 0; it < 12; ++it) {
    const int c0 = 32*it + 2*cg;
    const float4 x0 = *(const float4*)(xb + (size_t)c0*PN);
    const float4 x1 = *(const float4*)(xb + (size_t)(c0+1)*PN);
    const float w0 = wqkv[c0], w1 = wqkv[c0+1];
    qa.x += w0*x0.x + w1*x1.x;
    qa.y += w0*x0.y + w1*x1.y;
    qa.z += w0*x0.z + w1*x1.z;
    qa.w += w0*x0.w + w1*x1.w;
    const unsigned int p0 = (unsigned)f2bf(x0.x) | ((unsigned)f2bf(x1.x) << 16);
    const unsigned int p1 = (unsigned)f2bf(x0.y) | ((unsigned)f2bf(x1.y) << 16);
    const unsigned int p2 = (unsigned)f2bf(x0.z) | ((unsigned)f2bf(x1.z) << 16);
    const unsigned int p3 = (unsigned)f2bf(x0.w) | ((unsigned)f2bf(x1.w) << 16);
    const int cb = 2*c0;
    *(unsigned int*)(trb + (((r0+0)*768 + cb) ^ s0)) = p0;
    *(unsigned int*)(trb + (((r0+1)*768 + cb) ^ s1)) = p1;
    *(unsigned int*)(trb + (((r0+2)*768 + cb) ^ s2)) = p2;
    *(unsigned int*)(trb + (((r0+3)*768 + cb) ^ s3)) = p3;
  }
  // reduce q over the 16 c-groups: lanes differ in bits 4,5 within wave
  qa.x += __shfl_xor(qa.x, 16); qa.y += __shfl_xor(qa.y, 16);
  qa.z += __shfl_xor(qa.z, 16); qa.w += __shfl_xor(qa.w, 16);
  qa.x += __shfl_xor(qa.x, 32); qa.y += __shfl_xor(qa.y, 32);
  qa.z += __shfl_xor(qa.z, 32); qa.w += __shfl_xor(qa.w, 32);
  if (lane < 16) qw[wv_*16 + lane] = qa;
  __syncthreads();
  // copy image out (coalesced 16B)
  const int4* trs = (const int4*)tr;
  int4* dst = (int4*)(xbf + (size_t)bid * 24576);
  #pragma unroll
  for (int j = 0; j < 12; ++j) dst[j*256 + t] = trs[j*256 + t];
  if (t < 16) {
    float4 a0 = qw[t], a1 = qw[16+t], a2 = qw[32+t], a3 = qw[48+t];
    float4 o; o.x = a0.x+a1.x+a2.x+a3.x; o.y = a0.y+a1.y+a2.y+a3.y;
    o.z = a0.z+a1.z+a2.z+a3.z; o.w = a0.w+a1.w+a2.w+a3.w;
    *(float4*)(q + (size_t)bp*NNN + n0 + 4*t) = o;
  }
}

// K_WCVT2: W_v & W_out -> bf16, fragment-major tiling:
// idx(mf,ks,l15,g,j) = (mf*12+ks)*512 + l15*32 + g*8 + j ; row=16mf+l15, col=32ks+8g+j
__global__ __launch_bounds__(256) void k_wcvt2(
    const float* __restrict__ wqkv, const float* __restrict__ wout,
    unsigned short* __restrict__ wvt, unsigned short* __restrict__ woutt)
{
  const int i = blockIdx.x*256 + threadIdx.x;   // 0..294911
  const int e = (i < CC*CC) ? i : i - CC*CC;
  const int j   = e & 7;
  const int g   = (e >> 3) & 3;
  const int l15 = (e >> 5) & 15;
  const int rem = e >> 9;          // 0..287
  const int ks  = rem % 12;
  const int mf  = rem / 12;
  const int row = 16*mf + l15;
  const int col = 32*ks + 8*g + j;
  if (i < CC*CC) wvt[e]          = f2bf(wqkv[(size_t)(385 + row)*CC + col]);
  else           woutt[e]        = f2bf(wout[(size_t)row*CC + col]);
}

// K_SOFTMAX2: softmax over n per bp. grid=32, block=256.
__global__ __launch_bounds__(256) void k_softmax2(
    const float* __restrict__ q, const float* __restrict__ bqkv,
    float* __restrict__ scores)
{
  __shared__ float red[8];
  const int bp = blockIdx.x;
  const int t  = threadIdx.x;
  const int wv_ = t >> 6, ln = t & 63;
  const float bq = bqkv[0];
  float4 qv[4];
  float lmax = -1e30f;
  #pragma unroll
  for (int i = 0; i < 4; ++i) {
    const int n = i*1024 + t*4;
    float4 a = *(const float4*)(q + (size_t)bp*NNN + n);
    qv[i].x = a.x + bq; qv[i].y = a.y + bq; qv[i].z = a.z + bq; qv[i].w = a.w + bq;
    lmax = fmaxf(lmax, fmaxf(fmaxf(qv[i].x, qv[i].y), fmaxf(qv[i].z, qv[i].w)));
  }
  #pragma unroll
  for (int off = 32; off; off >>= 1) lmax = fmaxf(lmax, __shfl_xor(lmax, off));
  if (ln == 0) red[wv_] = lmax;
  __syncthreads();
  const float M = fmaxf(fmaxf(red[0], red[1]), fmaxf(red[2], red[3]));
  float lsum = 0.f;
  #pragma unroll
  for (int i = 0; i < 4; ++i) {
    qv[i].x = expf(qv[i].x - M); qv[i].y = expf(qv[i].y - M);
    qv[i].z = expf(qv[i].z - M); qv[i].w = expf(qv[i].w - M);
    lsum += qv[i].x + qv[i].y + qv[i].z + qv[i].w;
  }
  #pragma unroll
  for (int off = 32; off; off >>= 1) lsum += __shfl_xor(lsum, off);
  if (ln == 0) red[4 + wv_] = lsum;
  __syncthreads();
  const float inv = 1.f / (red[4] + red[5] + red[6] + red[7]);
  #pragma unroll
  for (int i = 0; i < 4; ++i) {
    const int n = i*1024 + t*4;
    float4 o; o.x=qv[i].x*inv; o.y=qv[i].y*inv; o.z=qv[i].z*inv; o.w=qv[i].w*inv;
    *(float4*)(scores + (size_t)bp*NNN + n) = o;
  }
}

// K_XS2: per (bp, tile): partial[bid][c] = sum_r xbf(r,c) * s[r]. grid=2048, block=384.
__global__ __launch_bounds__(384) void k_xs2(
    const unsigned short* __restrict__ xbf, const float* __restrict__ scores,
    float* __restrict__ partial)
{
  __shared__ __align__(16) char lds[49152];
  __shared__ float sl[64];
  const int bid = blockIdx.x;
  const int bp = bid >> 6, nt = bid & 63;
  const int t = threadIdx.x;
  const int w6 = t >> 6, lane = t & 63;
  const char* gsrc = (const char*)xbf + (size_t)bid * 49152;
  #pragma unroll
  for (int r = 0; r < 8; ++r) {
    const int loff = (r*6 + w6) * 1024;
    stage16(gsrc + loff + lane*16, lds + loff, lane);
  }
  if (t < 64) sl[t] = scores[(size_t)bp*NNN + nt*64 + t];
  __syncthreads();
  float acc = 0.f;
  #pragma unroll 8
  for (int r = 0; r < 64; ++r) {
    const unsigned short uv = *(const unsigned short*)(lds + ((r*768 + 2*t) ^ swz16(r)));
    acc += bf2f(uv) * sl[r];
  }
  partial[(size_t)bid*CC + t] = acc;
}

// K_CV2: xs[c] = sum_nt partial ; cv[bp][c] = b_k[c] + W_k[c].xs. grid=32, block=384.
__global__ __launch_bounds__(384) void k_cv2(
    const float* __restrict__ partial, const float* __restrict__ wqkv,
    const float* __restrict__ bqkv, float* __restrict__ cv)
{
  __shared__ float xsl[CC];
  const int bp = blockIdx.x;
  const int t  = threadIdx.x;
  float s = 0.f;
  #pragma unroll 8
  for (int nt = 0; nt < 64; ++nt) s += partial[((size_t)bp*64 + nt)*CC + t];
  xsl[t] = s;
  __syncthreads();
  float acc = bqkv[1 + t];
  const float* wk = wqkv + (size_t)(1 + t)*CC;
  #pragma unroll 8
  for (int c2 = 0; c2 < CC; ++c2) acc += wk[c2] * xsl[c2];
  cv[(size_t)bp*CC + t] = acc;
}

// K_MAIN2B: fused double GEMM, 128-n tiles (2 xbf images) per block.
// 1024 blocks x 768 thr (12 waves x 2 m-frags); LDS = 96KB (2 images).
// A-frags reused across 8 B-frags -> half the weight L2 traffic, deep
// latency cover. epi2 drains full 256B output rows (no write split).
__device__ __forceinline__ void gemm_t2(
    const unsigned short* __restrict__ wt, const char* lds,
    int w, int g, int l15, f32x4 acc[2][8])
{
  // wave w owns m-frags mf = 2w, 2w+1 ; A(mi,ks) at (mf*12+ks)*512
  const unsigned short* base = wt + (size_t)(2*w)*12*512 + l15*32 + g*8;
  s16x8 a[3][2];   // [slot = ks%3][mi]
  #pragma unroll
  for (int pf = 0; pf < 3; ++pf)
    #pragma unroll
    for (int mi = 0; mi < 2; ++mi)
      a[pf][mi] = *(const s16x8*)(base + ((size_t)mi*12 + pf)*512);
  #pragma unroll
  for (int ks = 0; ks < 12; ++ks) {
    const int slot = ks % 3;
    s16x8 bfr[8];
    #pragma unroll
    for (int nt = 0; nt < 8; ++nt) {
      const int row = 16*(nt & 3) + l15;
      const int byteb = (nt >> 2)*49152 + ((row*768 + 64*ks + 16*g) ^ swz16(row));
      bfr[nt] = *(const s16x8*)(lds + byteb);
    }
    #pragma unroll
    for (int mi = 0; mi < 2; ++mi)
      #pragma unroll
      for (int nt = 0; nt < 8; ++nt)
        acc[mi][nt] = __builtin_amdgcn_mfma_f32_16x16x32_bf16(
            a[slot][mi], bfr[nt], acc[mi][nt], 0, 0, 0);
    if (ks + 3 < 12) {
      #pragma unroll
      for (int mi = 0; mi < 2; ++mi)
        a[slot][mi] = *(const s16x8*)(base + ((size_t)mi*12 + ks + 3)*512);
    }
  }
}

__global__ __launch_bounds__(768, 1) void k_main2b(
    const unsigned short* __restrict__ xbf,
    const unsigned short* __restrict__ wvt,
    const unsigned short* __restrict__ woutt,
    const float* __restrict__ cv,
    const float* __restrict__ bqkv,
    const float* __restrict__ bout,
    float* __restrict__ out)
{
  __shared__ __align__(16) char lds[98304];   // 2 x 48KB images
  const int bid = blockIdx.x;          // 0..1023
  const int bp  = bid >> 5;            // 0..31
  const int t2  = bid & 31;            // 128-n tile index
  const int b = bp >> 2, p = bp & 3;
  const int tid = threadIdx.x;
  const int w = tid >> 6;              // 0..11
  const int lane = tid & 63;
  const int g = lane >> 4, l15 = lane & 15;

  // ---- stage 96KB = 2 adjacent images (async, contiguous)
  {
    const char* gsrc = (const char*)xbf + (size_t)(bp*64 + t2*2) * 49152;
    #pragma unroll
    for (int r = 0; r < 8; ++r) {
      const int loff = (r*12 + w) * 1024;
      stage16(gsrc + loff + lane*16, lds + loff, lane);
    }
  }
  __syncthreads();

  f32x4 acc[2][8];
  #pragma unroll
  for (int i = 0; i < 2; ++i)
    #pragma unroll
    for (int j = 0; j < 8; ++j) acc[i][j] = (f32x4){0.f,0.f,0.f,0.f};

  // ---- GEMM1: v = W_v @ x
  gemm_t2(wvt, lds, w, g, l15, acc);
  __syncthreads();

  // ---- epi1: relu(v + b_v) * cv -> bf16 back in place (both images)
  const float* cvp = cv + (size_t)bp*CC;
  #pragma unroll
  for (int mi = 0; mi < 2; ++mi) {
    const int m0 = 32*w + 16*mi + 4*g;
    const float* bv = bqkv + 385 + m0;
    const float b0 = bv[0], b1 = bv[1], b2 = bv[2], b3 = bv[3];
    const float4 cvv = *(const float4*)(cvp + m0);
    #pragma unroll
    for (int nt = 0; nt < 8; ++nt) {
      const int row = 16*(nt & 3) + l15;
      const f32x4 t = acc[mi][nt];
      u16x4 pk = { f2bf(fmaxf(t[0]+b0, 0.f)*cvv.x), f2bf(fmaxf(t[1]+b1, 0.f)*cvv.y),
                   f2bf(fmaxf(t[2]+b2, 0.f)*cvv.z), f2bf(fmaxf(t[3]+b3, 0.f)*cvv.w) };
      const int byte0 = (nt >> 2)*49152 + ((row*768 + 2*m0) ^ swz16(row));
      *(u16x4*)(lds + byte0) = pk;
    }
  }
  __syncthreads();

  #pragma unroll
  for (int i = 0; i < 2; ++i)
    #pragma unroll
    for (int j = 0; j < 8; ++j) acc[i][j] = (f32x4){0.f,0.f,0.f,0.f};

  // ---- GEMM2: out = W_out @ v
  gemm_t2(woutt, lds, w, g, l15, acc);

  // ---- epi2: +b_out; per half (64 n-cols): LDS [384][64] fp32 (96KB),
  // fill swizzle col ^= g<<3 (2 lanes/bank), drain full 256B rows (NT).
  float* fl = (float*)lds;
  #pragma unroll
  for (int half = 0; half < 2; ++half) {
    __syncthreads();   // GEMM2 LDS reads done / prev half drained
    #pragma unroll
    for (int mi = 0; mi < 2; ++mi) {
      const int m0 = 32*w + 16*mi + 4*g;
      const float4 bo = *(const float4*)(bout + m0);
      const int cswz = g << 3;
      #pragma unroll
      for (int nt2 = 0; nt2 < 4; ++nt2) {
        const f32x4 t = acc[mi][4*half + nt2];
        const int colh = (16*nt2 + l15) ^ cswz;
        fl[(m0+0)*64 + colh] = t[0] + bo.x;
        fl[(m0+1)*64 + colh] = t[1] + bo.y;
        fl[(m0+2)*64 + colh] = t[2] + bo.z;
        fl[(m0+3)*64 + colh] = t[3] + bo.w;
      }
    }
    __syncthreads();
    // drain 384x64 fp32: 768 thr x float4 x 8 passes; 16 lanes = 256B/row
    float* outb = out + (size_t)b*CC*PN + (size_t)p*NNN + t2*128 + half*64;
    #pragma unroll
    for (int ps = 0; ps < 8; ++ps) {
      const int idx = ps*768 + tid;              // 0..6143 float4 slots
      const int row = idx >> 4;                  // 0..383
      const int nq  = idx & 15;
      const int qb  = (nq*4) ^ (((row >> 2) & 3) << 3);
      const f32x4 v = *(const f32x4*)(fl + row*64 + qb);
      __builtin_nontemporal_store(v, (f32x4*)(outb + (size_t)row*PN + nq*4));
    }
  }
}

// ===========================================================================
// ========================= FALLBACK PATH (R3) ==============================
// ===========================================================================

__global__ __launch_bounds__(256) void k_qpart(
    const float* __restrict__ x, const float* __restrict__ wqkv,
    float* __restrict__ qpart)
{
  const int bid = blockIdx.x;
  const int seg = bid & 3;
  const int nc  = (bid >> 2) & 3;
  const int bp  = bid >> 4;
  const int b = bp >> 2, p = bp & 3;
  const int n = nc * 1024 + threadIdx.x * 4;
  const float* xb = x + (size_t)b*CC*PN + (size_t)p*NNN + n;
  float ax = 0.f, ay = 0.f, az = 0.f, aw = 0.f;
  const int c0 = seg * 96;
  #pragma unroll 8
  for (int c = c0; c < c0 + 96; ++c) {
    const float w = wqkv[c];
    const float4 xv = *(const float4*)(xb + (size_t)c*PN);
    ax += w*xv.x; ay += w*xv.y; az += w*xv.z; aw += w*xv.w;
  }
  float4 o; o.x=ax; o.y=ay; o.z=az; o.w=aw;
  *(float4*)(qpart + (size_t)(seg*NBP + bp)*NNN + n) = o;
}

__global__ __launch_bounds__(256) void k_softmax(
    const float* __restrict__ qpart, const float* __restrict__ bqkv,
    float* __restrict__ scores)
{
  __shared__ float red[8];
  const int bp = blockIdx.x;
  const int t  = threadIdx.x;
  const int wv_ = t >> 6, ln = t & 63;
  const float bq = bqkv[0];
  float4 q[4];
  float lmax = -1e30f;
  #pragma unroll
  for (int i = 0; i < 4; ++i) {
    const int n = i*1024 + t*4;
    const float* base = qpart + (size_t)bp*NNN + n;
    const float4 a = *(const float4*)(base);
    const float4 b1 = *(const float4*)(base + (size_t)NBP*NNN);
    const float4 c1 = *(const float4*)(base + (size_t)2*NBP*NNN);
    const float4 d1 = *(const float4*)(base + (size_t)3*NBP*NNN);
    q[i].x = a.x+b1.x+c1.x+d1.x + bq;
    q[i].y = a.y+b1.y+c1.y+d1.y + bq;
    q[i].z = a.z+b1.z+c1.z+d1.z + bq;
    q[i].w = a.w+b1.w+c1.w+d1.w + bq;
    lmax = fmaxf(lmax, fmaxf(fmaxf(q[i].x, q[i].y), fmaxf(q[i].z, q[i].w)));
  }
  #pragma unroll
  for (int off = 32; off; off >>= 1) lmax = fmaxf(lmax, __shfl_xor(lmax, off));
  if (ln == 0) red[wv_] = lmax;
  __syncthreads();
  const float M = fmaxf(fmaxf(red[0], red[1]), fmaxf(red[2], red[3]));
  float lsum = 0.f;
  #pragma unroll
  for (int i = 0; i < 4; ++i) {
    q[i].x = expf(q[i].x - M); q[i].y = expf(q[i].y - M);
    q[i].z = expf(q[i].z - M); q[i].w = expf(q[i].w - M);
    lsum += q[i].x + q[i].y + q[i].z + q[i].w;
  }
  #pragma unroll
  for (int off = 32; off; off >>= 1) lsum += __shfl_xor(lsum, off);
  if (ln == 0) red[4 + wv_] = lsum;
  __syncthreads();
  const float inv = 1.f / (red[4] + red[5] + red[6] + red[7]);
  #pragma unroll
  for (int i = 0; i < 4; ++i) {
    const int n = i*1024 + t*4;
    float4 o; o.x=q[i].x*inv; o.y=q[i].y*inv; o.z=q[i].z*inv; o.w=q[i].w*inv;
    *(float4*)(scores + (size_t)bp*NNN + n) = o;
  }
}

__global__ __launch_bounds__(256) void k_xs(
    const float* __restrict__ x, const float* __restrict__ scores,
    float* __restrict__ xs)
{
  __shared__ float red[4];
  const int c  = blockIdx.x;
  const int bp = blockIdx.y;
  const int b = bp >> 2, p = bp & 3;
  const float* xr = x + ((size_t)b*CC + c)*PN + (size_t)p*NNN;
  const float* sr = scores + (size_t)bp*NNN;
  float acc = 0.f;
  #pragma unroll
  for (int i = 0; i < 4; ++i) {
    const int n = i*1024 + threadIdx.x*4;
    const float4 xv = *(const float4*)(xr + n);
    const float4 sv = *(const float4*)(sr + n);
    acc += xv.x*sv.x + xv.y*sv.y + xv.z*sv.z + xv.w*sv.w;
  }
  #pragma unroll
  for (int off = 32; off; off >>= 1) acc += __shfl_xor(acc, off);
  if ((threadIdx.x & 63) == 0) red[threadIdx.x >> 6] = acc;
  __syncthreads();
  if (threadIdx.x == 0) xs[(size_t)bp*CC + c] = red[0]+red[1]+red[2]+red[3];
}

__global__ __launch_bounds__(256) void k_wcvt(
    const float* __restrict__ wqkv, const float* __restrict__ wout,
    unsigned short* __restrict__ wv, unsigned short* __restrict__ woutb)
{
  const int i = blockIdx.x*256 + threadIdx.x;
  if (i < CC*CC) wv[i] = f2bf(wqkv[385*CC + i]);
  else           woutb[i - CC*CC] = f2bf(wout[i - CC*CC]);
}

__global__ __launch_bounds__(384) void k_cv(
    const float* __restrict__ wqkv, const float* __restrict__ bqkv,
    const float* __restrict__ xs, float* __restrict__ cv)
{
  __shared__ float xsl[CC];
  const int bp = blockIdx.x;
  const int t  = threadIdx.x;
  xsl[t] = xs[(size_t)bp*CC + t];
  __syncthreads();
  float acc = bqkv[1 + t];
  const float* wk = wqkv + (size_t)(1 + t)*CC;
  #pragma unroll 8
  for (int c2 = 0; c2 < CC; ++c2) acc += wk[c2] * xsl[c2];
  cv[(size_t)bp*CC + t] = acc;
}

__device__ __forceinline__ void stage_load(
    const float* __restrict__ xb, int w, int chunk, float s[12])
{
  const int c0 = 96*chunk + 12*w;
  const float* xc = xb + (size_t)c0 * PN;
  #pragma unroll
  for (int k = 0; k < 12; ++k) s[k] = xc[(size_t)k * PN];
}

__device__ __forceinline__ void stage_write(
    char* lds, int w, int n, int chunk, const float s[12])
{
  const int swz = (n & 15) << 4;
  const int c0 = 96*chunk + 12*w;
  #pragma unroll
  for (int j = 0; j < 3; ++j) {
    u16x4 pk = { f2bf(s[4*j]), f2bf(s[4*j+1]), f2bf(s[4*j+2]), f2bf(s[4*j+3]) };
    const int byte0 = (n*768 + 2*(c0 + 4*j)) ^ swz;
    *(u16x4*)(lds + byte0) = pk;
  }
}

template<int KSN>
__device__ __forceinline__ void gemm_ks(
    const unsigned short* __restrict__ wa, const char* lds,
    int w, int g, int l15, int ks0, f32x4 acc[3][4])
{
  const unsigned short* wb = wa + (size_t)(48*w + l15)*CC + 8*g;
  s16x8 afr[2][3];
  #pragma unroll
  for (int mi = 0; mi < 3; ++mi)
    afr[0][mi] = *(const s16x8*)(wb + (size_t)(16*mi)*CC + 32*ks0);
  #pragma unroll
  for (int i = 0; i < KSN; ++i) {
    const int ks  = ks0 + i;
    const int cur = i & 1;
    if (i + 1 < KSN) {
      #pragma unroll
      for (int mi = 0; mi < 3; ++mi)
        afr[cur ^ 1][mi] = *(const s16x8*)(wb + (size_t)(16*mi)*CC + 32*(ks+1));
    }
    s16x8 bfr[4];
    #pragma unroll
    for (int nt = 0; nt < 4; ++nt) {
      const int row = 16*nt + l15;
      const int byteb = (row*768 + 64*ks + 16*g) ^ (l15 << 4);
      bfr[nt] = *(const s16x8*)(lds + byteb);
    }
    #pragma unroll
    for (int mi = 0; mi < 3; ++mi)
      #pragma unroll
      for (int nt = 0; nt < 4; ++nt)
        acc[mi][nt] = __builtin_amdgcn_mfma_f32_16x16x32_bf16(
            afr[cur][mi], bfr[nt], acc[mi][nt], 0, 0, 0);
  }
}

__global__ __launch_bounds__(512, 4) void k_main(
    const float* __restrict__ x,
    const unsigned short* __restrict__ wv,
    const unsigned short* __restrict__ woutb,
    const float* __restrict__ cv,
    const float* __restrict__ bqkv,
    const float* __restrict__ bout,
    float* __restrict__ out)
{
  __shared__ __align__(16) unsigned short lds_u16[64*384];
  char* lds = (char*)lds_u16;
  const int bid = blockIdx.x;
  const int nb  = bid & 63;
  const int bp  = bid >> 6;
  const int b = bp >> 2, p = bp & 3;
  const int n0 = nb * 64;
  const int tid  = threadIdx.x;
  const int w    = tid >> 6;
  const int lane = tid & 63;
  const int g    = lane >> 4;
  const int l15  = lane & 15;

  const float* xb = x + (size_t)b*CC*PN + (size_t)p*NNN + n0 + lane;

  float s[12];
  stage_load(xb, w, 0, s);
  stage_write(lds, w, lane, 0, s);
  stage_load(xb, w, 1, s);
  __syncthreads();

  f32x4 acc[3][4];
  #pragma unroll
  for (int i = 0; i < 3; ++i)
    #pragma unroll
    for (int j = 0; j < 4; ++j) acc[i][j] = (f32x4){0.f,0.f,0.f,0.f};

  for (int c = 0; c < 4; ++c) {
    gemm_ks<3>(wv, lds, w, g, l15, 3*c, acc);
    if (c < 3) {
      stage_write(lds, w, lane, c+1, s);
      if (c < 2) stage_load(xb, w, c+2, s);
    }
    __syncthreads();
  }

  const float* cvp = cv + (size_t)bp*CC;
  #pragma unroll
  for (int mi = 0; mi < 3; ++mi) {
    const int m0 = 48*w + 16*mi + 4*g;
    const float* bv = bqkv + 385 + m0;
    const float b0 = bv[0], b1 = bv[1], b2 = bv[2], b3 = bv[3];
    const float4 cvv = *(const float4*)(cvp + m0);
    #pragma unroll
    for (int nt = 0; nt < 4; ++nt) {
      const int row = 16*nt + l15;
      const f32x4 t = acc[mi][nt];
      u16x4 pk = { f2bf(fmaxf(t[0]+b0, 0.f)*cvv.x), f2bf(fmaxf(t[1]+b1, 0.f)*cvv.y),
                   f2bf(fmaxf(t[2]+b2, 0.f)*cvv.z), f2bf(fmaxf(t[3]+b3, 0.f)*cvv.w) };
      const int byte0 = (row*768 + 2*m0) ^ (l15 << 4);
      *(u16x4*)(lds + byte0) = pk;
    }
  }
  __syncthreads();

  #pragma unroll
  for (int i = 0; i < 3; ++i)
    #pragma unroll
    for (int j = 0; j < 4; ++j) acc[i][j] = (f32x4){0.f,0.f,0.f,0.f};

  gemm_ks<12>(woutb, lds, w, g, l15, 0, acc);

  #pragma unroll
  for (int mi = 0; mi < 3; ++mi) {
    const int m0 = 48*w + 16*mi + 4*g;
    const float4 bo = *(const float4*)(bout + m0);
    #pragma unroll
    for (int nt = 0; nt < 4; ++nt) {
      const int nn = n0 + 16*nt + l15;
      const f32x4 t = acc[mi][nt];
      float* ob = out + ((size_t)b*CC + m0)*PN + (size_t)p*NNN + nn;
      ob[0]            = t[0] + bo.x;
      ob[(size_t)PN]   = t[1] + bo.y;
      ob[2*(size_t)PN] = t[2] + bo.z;
      ob[3*(size_t)PN] = t[3] + bo.w;
    }
  }
}

// ---------------------------------------------------------------------------
extern "C" void kernel_launch(void* const* d_in, const int* in_sizes, int n_in,
                              void* d_out, int out_size, void* d_ws, size_t ws_size,
                              hipStream_t stream) {
  const float* x    = (const float*)d_in[0];
  const float* wqkv = (const float*)d_in[1];
  const float* bqkv = (const float*)d_in[2];
  const float* wout = (const float*)d_in[3];
  const float* bout = (const float*)d_in[4];
  float* out = (float*)d_out;
  char* ws = (char*)d_ws;

  // fast-path workspace layout (~100.6 MB)
  const size_t OFF_XBF = 0;                       // 2048*49152 = 100663296
  const size_t OFF_Q   = 100663296;               // 524288
  const size_t OFF_SC  = 101187584;               // 524288
  const size_t OFF_PT  = 101711872;               // 3145728
  const size_t OFF_WVT = 104857600;               // 294912
  const size_t OFF_WOT = 105152512;               // 294912
  const size_t OFF_CV  = 105447424;               // 49152
  const size_t NEED    = 105496576;

  if (ws_size >= NEED) {
    unsigned short* xbf   = (unsigned short*)(ws + OFF_XBF);
    float* q              = (float*)(ws + OFF_Q);
    float* scores         = (float*)(ws + OFF_SC);
    float* partial        = (float*)(ws + OFF_PT);
    unsigned short* wvt   = (unsigned short*)(ws + OFF_WVT);
    unsigned short* woutt = (unsigned short*)(ws + OFF_WOT);
    float* cvp            = (float*)(ws + OFF_CV);

    hipLaunchKernelGGL(k_pre,      dim3(2048), dim3(256), 0, stream, x, wqkv, xbf, q);
    hipLaunchKernelGGL(k_wcvt2,    dim3(1152), dim3(256), 0, stream, wqkv, wout, wvt, woutt);
    hipLaunchKernelGGL(k_softmax2, dim3(32),   dim3(256), 0, stream, q, bqkv, scores);
    hipLaunchKernelGGL(k_xs2,      dim3(2048), dim3(384), 0, stream, xbf, scores, partial);
    hipLaunchKernelGGL(k_cv2,      dim3(32),   dim3(384), 0, stream, partial, wqkv, bqkv, cvp);
    hipLaunchKernelGGL(k_main2b,   dim3(1024), dim3(768), 0, stream, xbf, wvt, woutt, cvp, bqkv, bout, out);
  } else {
    float* scores         = (float*)(ws);
    float* qpart          = (float*)(ws + 524288);
    float* xs             = (float*)(ws + 2621440);
    unsigned short* wv    = (unsigned short*)(ws + 2719744);
    unsigned short* woutb = (unsigned short*)(ws + 3014656);
    float* cvp            = (float*)(ws + 3309568);

    hipLaunchKernelGGL(k_qpart,   dim3(512),      dim3(256), 0, stream, x, wqkv, qpart);
    hipLaunchKernelGGL(k_wcvt,    dim3(1152),     dim3(256), 0, stream, wqkv, wout, wv, woutb);
    hipLaunchKernelGGL(k_softmax, dim3(32),       dim3(256), 0, stream, qpart, bqkv, scores);
    hipLaunchKernelGGL(k_xs,      dim3(CC, NBP),  dim3(256), 0, stream, x, scores, xs);
    hipLaunchKernelGGL(k_cv,      dim3(NBP),      dim3(384), 0, stream, wqkv, bqkv, xs, cvp);
    hipLaunchKernelGGL(k_main,    dim3(2048),     dim3(512), 0, stream, x, wv, woutb, cvp, bqkv, bout, out);
  }
}

// Round 12
// 225.131 us; speedup vs baseline: 2.3337x; 1.0361x over previous
//
#include <hip/hip_runtime.h>
#include <hip/hip_bf16.h>
#include <stdint.h>

// Problem constants
#define CC   384          // EMBED_DIM
#define BB   8
#define PP   4
#define NNN  4096
#define NBP  32           // B*P slices
#define PN   (PP*NNN)     // stride between channels in x/out (=16384 floats)

#define AS1 __attribute__((address_space(1)))
#define AS3 __attribute__((address_space(3)))

typedef float  f32x4 __attribute__((ext_vector_type(4)));
typedef short  s16x8 __attribute__((ext_vector_type(8)));
typedef unsigned short u16x4 __attribute__((ext_vector_type(4)));

__device__ __forceinline__ unsigned short f2bf(float f) {
  unsigned int u = __float_as_uint(f);
  u += 0x7fffu + ((u >> 16) & 1u);
  return (unsigned short)(u >> 16);
}
__device__ __forceinline__ float bf2f(unsigned short u) {
  return __uint_as_float(((unsigned int)u) << 16);
}

// Image swizzle: nonlinear in low row bits so both 16-consecutive-row reads
// (consumer) and stride-4-row writes (producer) spread over 8 bank groups.
__device__ __forceinline__ int swz16(int r) {
  return ((r ^ (r >> 2)) & 15) << 4;
}

// async global->LDS, 16B per lane. g is per-lane, l is wave-uniform base.
__device__ __forceinline__ void stage16(const char* g, char* l_uniform, int lane) {
#if defined(__has_builtin) && __has_builtin(__builtin_amdgcn_global_load_lds)
  __builtin_amdgcn_global_load_lds((const AS1 unsigned int*)g,
                                   (AS3 unsigned int*)l_uniform, 16, 0, 0);
#else
  *(int4*)(l_uniform + lane*16) = *(const int4*)g;
#endif
}

// ===========================================================================
// ============================ FAST PATH ====================================
// ===========================================================================

// K_PRE: per (bp, 64-n tile): transpose x -> swz16-swizzled bf16 LDS image
// (48KB to xbf[bid]); fold q (complete for this tile's 64 n) in the same
// pass; then LOCAL flash-style softmax: m_t = max q, e[n] = exp(q-m_t),
// and unnormalized xs-partials  partial[bid][c] = sum_n img[n][c]*e[n].
// grid=2048, block=256.
__global__ __launch_bounds__(256) void k_pre(
    const float* __restrict__ x, const float* __restrict__ wqkv,
    unsigned short* __restrict__ xbf, float* __restrict__ q,
    float* __restrict__ partial, float* __restrict__ mt)
{
  __shared__ __align__(16) unsigned short tr[24576];   // 48KB image
  __shared__ float4 qw[64];
  __shared__ float4 qfin4[16];
  __shared__ float e_sh[64];
  __shared__ float m_sh;
  char* trb = (char*)tr;
  const int bid = blockIdx.x;
  const int bp = bid >> 6, nt = bid & 63;
  const int b = bp >> 2, p = bp & 3;
  const int n0 = nt * 64;
  const int t  = threadIdx.x;
  const int wv_ = t >> 6, lane = t & 63;
  const int cg = t >> 4, nv = t & 15;     // c-pair group 0..15, n-subvec 0..15
  const int r0 = 4 * nv;
  const float* xb = x + (size_t)b*CC*PN + (size_t)p*NNN + n0 + r0;
  const int s0 = swz16(r0+0), s1 = swz16(r0+1), s2 = swz16(r0+2), s3 = swz16(r0+3);

  float4 qa = {0.f, 0.f, 0.f, 0.f};
  #pragma unroll 3
  for (int it = 0; it < 12; ++it) {
    const int c0 = 32*it + 2*cg;
    const float4 x0 = *(const float4*)(xb + (size_t)c0*PN);
    const float4 x1 = *(const float4*)(xb + (size_t)(c0+1)*PN);
    const float w0 = wqkv[c0], w1 = wqkv[c0+1];
    qa.x += w0*x0.x + w1*x1.x;
    qa.y += w0*x0.y + w1*x1.y;
    qa.z += w0*x0.z + w1*x1.z;
    qa.w += w0*x0.w + w1*x1.w;
    const unsigned int p0 = (unsigned)f2bf(x0.x) | ((unsigned)f2bf(x1.x) << 16);
    const unsigned int p1 = (unsigned)f2bf(x0.y) | ((unsigned)f2bf(x1.y) << 16);
    const unsigned int p2 = (unsigned)f2bf(x0.z) | ((unsigned)f2bf(x1.z) << 16);
    const unsigned int p3 = (unsigned)f2bf(x0.w) | ((unsigned)f2bf(x1.w) << 16);
    const int cb = 2*c0;
    *(unsigned int*)(trb + (((r0+0)*768 + cb) ^ s0)) = p0;
    *(unsigned int*)(trb + (((r0+1)*768 + cb) ^ s1)) = p1;
    *(unsigned int*)(trb + (((r0+2)*768 + cb) ^ s2)) = p2;
    *(unsigned int*)(trb + (((r0+3)*768 + cb) ^ s3)) = p3;
  }
  // reduce q over the 16 c-groups: lanes differ in bits 4,5 within wave
  qa.x += __shfl_xor(qa.x, 16); qa.y += __shfl_xor(qa.y, 16);
  qa.z += __shfl_xor(qa.z, 16); qa.w += __shfl_xor(qa.w, 16);
  qa.x += __shfl_xor(qa.x, 32); qa.y += __shfl_xor(qa.y, 32);
  qa.z += __shfl_xor(qa.z, 32); qa.w += __shfl_xor(qa.w, 32);
  if (lane < 16) qw[wv_*16 + lane] = qa;
  __syncthreads();
  // copy image out (coalesced 16B)
  const int4* trs = (const int4*)tr;
  int4* dst = (int4*)(xbf + (size_t)bid * 24576);
  #pragma unroll
  for (int j = 0; j < 12; ++j) dst[j*256 + t] = trs[j*256 + t];
  if (t < 16) {
    float4 a0 = qw[t], a1 = qw[16+t], a2 = qw[32+t], a3 = qw[48+t];
    float4 o; o.x = a0.x+a1.x+a2.x+a3.x; o.y = a0.y+a1.y+a2.y+a3.y;
    o.z = a0.z+a1.z+a2.z+a3.z; o.w = a0.w+a1.w+a2.w+a3.w;
    *(float4*)(q + (size_t)bp*NNN + n0 + 4*t) = o;
    qfin4[t] = o;
    float m4 = fmaxf(fmaxf(o.x, o.y), fmaxf(o.z, o.w));
    #pragma unroll
    for (int off = 8; off; off >>= 1) m4 = fmaxf(m4, __shfl_xor(m4, off));
    if (t == 0) { m_sh = m4; mt[bid] = m4; }
  }
  __syncthreads();
  if (t < 64) {
    const float* qf = (const float*)qfin4;
    e_sh[t] = expf(qf[t] - m_sh);
  }
  __syncthreads();
  // xs partials: thread handles c = t (and t+256 when <384)
  for (int c = t; c < CC; c += 256) {
    float acc = 0.f;
    #pragma unroll 8
    for (int r = 0; r < 64; ++r) {
      const unsigned short uv = *(const unsigned short*)(trb + ((r*768 + 2*c) ^ swz16(r)));
      acc += bf2f(uv) * e_sh[r];
    }
    partial[(size_t)bid*CC + c] = acc;
  }
}

// K_WCVT2: W_v & W_out -> bf16, fragment-major tiling:
// idx(mf,ks,l15,g,j) = (mf*12+ks)*512 + l15*32 + g*8 + j ; row=16mf+l15, col=32ks+8g+j
__global__ __launch_bounds__(256) void k_wcvt2(
    const float* __restrict__ wqkv, const float* __restrict__ wout,
    unsigned short* __restrict__ wvt, unsigned short* __restrict__ woutt)
{
  const int i = blockIdx.x*256 + threadIdx.x;   // 0..294911
  const int e = (i < CC*CC) ? i : i - CC*CC;
  const int j   = e & 7;
  const int g   = (e >> 3) & 3;
  const int l15 = (e >> 5) & 15;
  const int rem = e >> 9;          // 0..287
  const int ks  = rem % 12;
  const int mf  = rem / 12;
  const int row = 16*mf + l15;
  const int col = 32*ks + 8*g + j;
  if (i < CC*CC) wvt[e]          = f2bf(wqkv[(size_t)(385 + row)*CC + col]);
  else           woutt[e]        = f2bf(wout[(size_t)row*CC + col]);
}

// K_QMZ: global softmax stats M[bp], Z[bp] from q. grid=32, block=256.
__global__ __launch_bounds__(256) void k_qmz(
    const float* __restrict__ q, const float* __restrict__ bqkv,
    float* __restrict__ MZ)
{
  __shared__ float red[8];
  const int bp = blockIdx.x;
  const int t  = threadIdx.x;
  const int wv_ = t >> 6, ln = t & 63;
  const float bq = bqkv[0];
  float4 qv[4];
  float lmax = -1e30f;
  #pragma unroll
  for (int i = 0; i < 4; ++i) {
    const int n = i*1024 + t*4;
    float4 a = *(const float4*)(q + (size_t)bp*NNN + n);
    qv[i].x = a.x + bq; qv[i].y = a.y + bq; qv[i].z = a.z + bq; qv[i].w = a.w + bq;
    lmax = fmaxf(lmax, fmaxf(fmaxf(qv[i].x, qv[i].y), fmaxf(qv[i].z, qv[i].w)));
  }
  #pragma unroll
  for (int off = 32; off; off >>= 1) lmax = fmaxf(lmax, __shfl_xor(lmax, off));
  if (ln == 0) red[wv_] = lmax;
  __syncthreads();
  const float M = fmaxf(fmaxf(red[0], red[1]), fmaxf(red[2], red[3]));
  float lsum = 0.f;
  #pragma unroll
  for (int i = 0; i < 4; ++i) {
    lsum += expf(qv[i].x - M) + expf(qv[i].y - M)
          + expf(qv[i].z - M) + expf(qv[i].w - M);
  }
  #pragma unroll
  for (int off = 32; off; off >>= 1) lsum += __shfl_xor(lsum, off);
  if (ln == 0) red[4 + wv_] = lsum;
  __syncthreads();
  if (t == 0) {
    MZ[2*bp]   = M;
    MZ[2*bp+1] = red[4] + red[5] + red[6] + red[7];
  }
}

// K_CV3: xs[c] = (1/Z) sum_t partial[t][c]*exp(m_t - M)  (q-bias folded via
// M,Z which already include it? NO: m_t/partials exclude bq; scores with bq:
// softmax(q+bq) == softmax(q), so bq cancels exactly — partials consistent).
// Then cv[bp][c] = b_k[c] + W_k[c].xs. grid=32, block=384.
__global__ __launch_bounds__(384) void k_cv3(
    const float* __restrict__ partial, const float* __restrict__ mt,
    const float* __restrict__ MZ, const float* __restrict__ bqkv,
    const float* __restrict__ wqkv, float* __restrict__ cv)
{
  __shared__ float xsl[CC];
  __shared__ float esc[64];
  const int bp = blockIdx.x;
  const int t  = threadIdx.x;
  const float bq = bqkv[0];
  // M was computed on q+bq; m_t on raw q. exp((m_t+bq) - M) aligns them.
  const float M = MZ[2*bp];
  const float invZ = 1.f / MZ[2*bp+1];
  if (t < 64) esc[t] = expf(mt[bp*64 + t] + bq - M);
  __syncthreads();
  float s = 0.f;
  #pragma unroll 8
  for (int t2 = 0; t2 < 64; ++t2)
    s += partial[((size_t)bp*64 + t2)*CC + t] * esc[t2];
  xsl[t] = s * invZ;
  __syncthreads();
  float acc = bqkv[1 + t];
  const float* wk = wqkv + (size_t)(1 + t)*CC;
  #pragma unroll 8
  for (int c2 = 0; c2 < CC; ++c2) acc += wk[c2] * xsl[c2];
  cv[(size_t)bp*CC + t] = acc;
}

// K_MAIN2B: fused double GEMM, 128-n tiles (2 xbf images) per block.
// 1024 blocks x 768 thr (12 waves x 2 m-frags); LDS = 96KB (2 images).
__device__ __forceinline__ void gemm_t2(
    const unsigned short* __restrict__ wt, const char* lds,
    int w, int g, int l15, f32x4 acc[2][8])
{
  // wave w owns m-frags mf = 2w, 2w+1 ; A(mi,ks) at (mf*12+ks)*512
  const unsigned short* base = wt + (size_t)(2*w)*12*512 + l15*32 + g*8;
  s16x8 a[3][2];   // [slot = ks%3][mi]
  #pragma unroll
  for (int pf = 0; pf < 3; ++pf)
    #pragma unroll
    for (int mi = 0; mi < 2; ++mi)
      a[pf][mi] = *(const s16x8*)(base + ((size_t)mi*12 + pf)*512);
  #pragma unroll
  for (int ks = 0; ks < 12; ++ks) {
    const int slot = ks % 3;
    s16x8 bfr[8];
    #pragma unroll
    for (int nt = 0; nt < 8; ++nt) {
      const int row = 16*(nt & 3) + l15;
      const int byteb = (nt >> 2)*49152 + ((row*768 + 64*ks + 16*g) ^ swz16(row));
      bfr[nt] = *(const s16x8*)(lds + byteb);
    }
    #pragma unroll
    for (int mi = 0; mi < 2; ++mi)
      #pragma unroll
      for (int nt = 0; nt < 8; ++nt)
        acc[mi][nt] = __builtin_amdgcn_mfma_f32_16x16x32_bf16(
            a[slot][mi], bfr[nt], acc[mi][nt], 0, 0, 0);
    if (ks + 3 < 12) {
      #pragma unroll
      for (int mi = 0; mi < 2; ++mi)
        a[slot][mi] = *(const s16x8*)(base + ((size_t)mi*12 + ks + 3)*512);
    }
  }
}

__global__ __launch_bounds__(768, 1) void k_main2b(
    const unsigned short* __restrict__ xbf,
    const unsigned short* __restrict__ wvt,
    const unsigned short* __restrict__ woutt,
    const float* __restrict__ cv,
    const float* __restrict__ bqkv,
    const float* __restrict__ bout,
    float* __restrict__ out)
{
  __shared__ __align__(16) char lds[98304];   // 2 x 48KB images
  const int bid = blockIdx.x;          // 0..1023
  const int bp  = bid >> 5;            // 0..31
  const int t2  = bid & 31;            // 128-n tile index
  const int b = bp >> 2, p = bp & 3;
  const int tid = threadIdx.x;
  const int w = tid >> 6;              // 0..11
  const int lane = tid & 63;
  const int g = lane >> 4, l15 = lane & 15;

  // ---- stage 96KB = 2 adjacent images (async, contiguous)
  {
    const char* gsrc = (const char*)xbf + (size_t)(bp*64 + t2*2) * 49152;
    #pragma unroll
    for (int r = 0; r < 8; ++r) {
      const int loff = (r*12 + w) * 1024;
      stage16(gsrc + loff + lane*16, lds + loff, lane);
    }
  }
  __syncthreads();

  f32x4 acc[2][8];
  #pragma unroll
  for (int i = 0; i < 2; ++i)
    #pragma unroll
    for (int j = 0; j < 8; ++j) acc[i][j] = (f32x4){0.f,0.f,0.f,0.f};

  // ---- GEMM1: v = W_v @ x
  gemm_t2(wvt, lds, w, g, l15, acc);
  __syncthreads();

  // ---- epi1: relu(v + b_v) * cv -> bf16 back in place (both images)
  const float* cvp = cv + (size_t)bp*CC;
  #pragma unroll
  for (int mi = 0; mi < 2; ++mi) {
    const int m0 = 32*w + 16*mi + 4*g;
    const float* bv = bqkv + 385 + m0;
    const float b0 = bv[0], b1 = bv[1], b2 = bv[2], b3 = bv[3];
    const float4 cvv = *(const float4*)(cvp + m0);
    #pragma unroll
    for (int nt = 0; nt < 8; ++nt) {
      const int row = 16*(nt & 3) + l15;
      const f32x4 t = acc[mi][nt];
      u16x4 pk = { f2bf(fmaxf(t[0]+b0, 0.f)*cvv.x), f2bf(fmaxf(t[1]+b1, 0.f)*cvv.y),
                   f2bf(fmaxf(t[2]+b2, 0.f)*cvv.z), f2bf(fmaxf(t[3]+b3, 0.f)*cvv.w) };
      const int byte0 = (nt >> 2)*49152 + ((row*768 + 2*m0) ^ swz16(row));
      *(u16x4*)(lds + byte0) = pk;
    }
  }
  __syncthreads();

  #pragma unroll
  for (int i = 0; i < 2; ++i)
    #pragma unroll
    for (int j = 0; j < 8; ++j) acc[i][j] = (f32x4){0.f,0.f,0.f,0.f};

  // ---- GEMM2: out = W_out @ v
  gemm_t2(woutt, lds, w, g, l15, acc);

  // ---- epi2: +b_out; per half (64 n-cols): LDS [384][64] fp32 (96KB),
  // fill swizzle col ^= g<<3, drain full 256B rows (NT).
  float* fl = (float*)lds;
  #pragma unroll
  for (int half = 0; half < 2; ++half) {
    __syncthreads();   // GEMM2 LDS reads done / prev half drained
    #pragma unroll
    for (int mi = 0; mi < 2; ++mi) {
      const int m0 = 32*w + 16*mi + 4*g;
      const float4 bo = *(const float4*)(bout + m0);
      const int cswz = g << 3;
      #pragma unroll
      for (int nt2 = 0; nt2 < 4; ++nt2) {
        const f32x4 t = acc[mi][4*half + nt2];
        const int colh = (16*nt2 + l15) ^ cswz;
        fl[(m0+0)*64 + colh] = t[0] + bo.x;
        fl[(m0+1)*64 + colh] = t[1] + bo.y;
        fl[(m0+2)*64 + colh] = t[2] + bo.z;
        fl[(m0+3)*64 + colh] = t[3] + bo.w;
      }
    }
    __syncthreads();
    // drain 384x64 fp32: 768 thr x float4 x 8 passes; 16 lanes = 256B/row
    float* outb = out + (size_t)b*CC*PN + (size_t)p*NNN + t2*128 + half*64;
    #pragma unroll
    for (int ps = 0; ps < 8; ++ps) {
      const int idx = ps*768 + tid;              // 0..6143 float4 slots
      const int row = idx >> 4;                  // 0..383
      const int nq  = idx & 15;
      const int qb  = (nq*4) ^ (((row >> 2) & 3) << 3);
      const f32x4 v = *(const f32x4*)(fl + row*64 + qb);
      __builtin_nontemporal_store(v, (f32x4*)(outb + (size_t)row*PN + nq*4));
    }
  }
}

// ===========================================================================
// ========================= FALLBACK PATH (R3) ==============================
// ===========================================================================

__global__ __launch_bounds__(256) void k_qpart(
    const float* __restrict__ x, const float* __restrict__ wqkv,
    float* __restrict__ qpart)
{
  const int bid = blockIdx.x;
  const int seg = bid & 3;
  const int nc  = (bid >> 2) & 3;
  const int bp  = bid >> 4;
  const int b = bp >> 2, p = bp & 3;
  const int n = nc * 1024 + threadIdx.x * 4;
  const float* xb = x + (size_t)b*CC*PN + (size_t)p*NNN + n;
  float ax = 0.f, ay = 0.f, az = 0.f, aw = 0.f;
  const int c0 = seg * 96;
  #pragma unroll 8
  for (int c = c0; c < c0 + 96; ++c) {
    const float w = wqkv[c];
    const float4 xv = *(const float4*)(xb + (size_t)c*PN);
    ax += w*xv.x; ay += w*xv.y; az += w*xv.z; aw += w*xv.w;
  }
  float4 o; o.x=ax; o.y=ay; o.z=az; o.w=aw;
  *(float4*)(qpart + (size_t)(seg*NBP + bp)*NNN + n) = o;
}

__global__ __launch_bounds__(256) void k_softmax(
    const float* __restrict__ qpart, const float* __restrict__ bqkv,
    float* __restrict__ scores)
{
  __shared__ float red[8];
  const int bp = blockIdx.x;
  const int t  = threadIdx.x;
  const int wv_ = t >> 6, ln = t & 63;
  const float bq = bqkv[0];
  float4 q[4];
  float lmax = -1e30f;
  #pragma unroll
  for (int i = 0; i < 4; ++i) {
    const int n = i*1024 + t*4;
    const float* base = qpart + (size_t)bp*NNN + n;
    const float4 a = *(const float4*)(base);
    const float4 b1 = *(const float4*)(base + (size_t)NBP*NNN);
    const float4 c1 = *(const float4*)(base + (size_t)2*NBP*NNN);
    const float4 d1 = *(const float4*)(base + (size_t)3*NBP*NNN);
    q[i].x = a.x+b1.x+c1.x+d1.x + bq;
    q[i].y = a.y+b1.y+c1.y+d1.y + bq;
    q[i].z = a.z+b1.z+c1.z+d1.z + bq;
    q[i].w = a.w+b1.w+c1.w+d1.w + bq;
    lmax = fmaxf(lmax, fmaxf(fmaxf(q[i].x, q[i].y), fmaxf(q[i].z, q[i].w)));
  }
  #pragma unroll
  for (int off = 32; off; off >>= 1) lmax = fmaxf(lmax, __shfl_xor(lmax, off));
  if (ln == 0) red[wv_] = lmax;
  __syncthreads();
  const float M = fmaxf(fmaxf(red[0], red[1]), fmaxf(red[2], red[3]));
  float lsum = 0.f;
  #pragma unroll
  for (int i = 0; i < 4; ++i) {
    q[i].x = expf(q[i].x - M); q[i].y = expf(q[i].y - M);
    q[i].z = expf(q[i].z - M); q[i].w = expf(q[i].w - M);
    lsum += q[i].x + q[i].y + q[i].z + q[i].w;
  }
  #pragma unroll
  for (int off = 32; off; off >>= 1) lsum += __shfl_xor(lsum, off);
  if (ln == 0) red[4 + wv_] = lsum;
  __syncthreads();
  const float inv = 1.f / (red[4] + red[5] + red[6] + red[7]);
  #pragma unroll
  for (int i = 0; i < 4; ++i) {
    const int n = i*1024 + t*4;
    float4 o; o.x=q[i].x*inv; o.y=q[i].y*inv; o.z=q[i].z*inv; o.w=q[i].w*inv;
    *(float4*)(scores + (size_t)bp*NNN + n) = o;
  }
}

__global__ __launch_bounds__(256) void k_xs(
    const float* __restrict__ x, const float* __restrict__ scores,
    float* __restrict__ xs)
{
  __shared__ float red[4];
  const int c  = blockIdx.x;
  const int bp = blockIdx.y;
  const int b = bp >> 2, p = bp & 3;
  const float* xr = x + ((size_t)b*CC + c)*PN + (size_t)p*NNN;
  const float* sr = scores + (size_t)bp*NNN;
  float acc = 0.f;
  #pragma unroll
  for (int i = 0; i < 4; ++i) {
    const int n = i*1024 + threadIdx.x*4;
    const float4 xv = *(const float4*)(xr + n);
    const float4 sv = *(const float4*)(sr + n);
    acc += xv.x*sv.x + xv.y*sv.y + xv.z*sv.z + xv.w*sv.w;
  }
  #pragma unroll
  for (int off = 32; off; off >>= 1) acc += __shfl_xor(acc, off);
  if ((threadIdx.x & 63) == 0) red[threadIdx.x >> 6] = acc;
  __syncthreads();
  if (threadIdx.x == 0) xs[(size_t)bp*CC + c] = red[0]+red[1]+red[2]+red[3];
}

__global__ __launch_bounds__(256) void k_wcvt(
    const float* __restrict__ wqkv, const float* __restrict__ wout,
    unsigned short* __restrict__ wv, unsigned short* __restrict__ woutb)
{
  const int i = blockIdx.x*256 + threadIdx.x;
  if (i < CC*CC) wv[i] = f2bf(wqkv[385*CC + i]);
  else           woutb[i - CC*CC] = f2bf(wout[i - CC*CC]);
}

__global__ __launch_bounds__(384) void k_cv(
    const float* __restrict__ wqkv, const float* __restrict__ bqkv,
    const float* __restrict__ xs, float* __restrict__ cv)
{
  __shared__ float xsl[CC];
  const int bp = blockIdx.x;
  const int t  = threadIdx.x;
  xsl[t] = xs[(size_t)bp*CC + t];
  __syncthreads();
  float acc = bqkv[1 + t];
  const float* wk = wqkv + (size_t)(1 + t)*CC;
  #pragma unroll 8
  for (int c2 = 0; c2 < CC; ++c2) acc += wk[c2] * xsl[c2];
  cv[(size_t)bp*CC + t] = acc;
}

__device__ __forceinline__ void stage_load(
    const float* __restrict__ xb, int w, int chunk, float s[12])
{
  const int c0 = 96*chunk + 12*w;
  const float* xc = xb + (size_t)c0 * PN;
  #pragma unroll
  for (int k = 0; k < 12; ++k) s[k] = xc[(size_t)k * PN];
}

__device__ __forceinline__ void stage_write(
    char* lds, int w, int n, int chunk, const float s[12])
{
  const int swz = (n & 15) << 4;
  const int c0 = 96*chunk + 12*w;
  #pragma unroll
  for (int j = 0; j < 3; ++j) {
    u16x4 pk = { f2bf(s[4*j]), f2bf(s[4*j+1]), f2bf(s[4*j+2]), f2bf(s[4*j+3]) };
    const int byte0 = (n*768 + 2*(c0 + 4*j)) ^ swz;
    *(u16x4*)(lds + byte0) = pk;
  }
}

template<int KSN>
__device__ __forceinline__ void gemm_ks(
    const unsigned short* __restrict__ wa, const char* lds,
    int w, int g, int l15, int ks0, f32x4 acc[3][4])
{
  const unsigned short* wb = wa + (size_t)(48*w + l15)*CC + 8*g;
  s16x8 afr[2][3];
  #pragma unroll
  for (int mi = 0; mi < 3; ++mi)
    afr[0][mi] = *(const s16x8*)(wb + (size_t)(16*mi)*CC + 32*ks0);
  #pragma unroll
  for (int i = 0; i < KSN; ++i) {
    const int ks  = ks0 + i;
    const int cur = i & 1;
    if (i + 1 < KSN) {
      #pragma unroll
      for (int mi = 0; mi < 3; ++mi)
        afr[cur ^ 1][mi] = *(const s16x8*)(wb + (size_t)(16*mi)*CC + 32*(ks+1));
    }
    s16x8 bfr[4];
    #pragma unroll
    for (int nt = 0; nt < 4; ++nt) {
      const int row = 16*nt + l15;
      const int byteb = (row*768 + 64*ks + 16*g) ^ (l15 << 4);
      bfr[nt] = *(const s16x8*)(lds + byteb);
    }
    #pragma unroll
    for (int mi = 0; mi < 3; ++mi)
      #pragma unroll
      for (int nt = 0; nt < 4; ++nt)
        acc[mi][nt] = __builtin_amdgcn_mfma_f32_16x16x32_bf16(
            afr[cur][mi], bfr[nt], acc[mi][nt], 0, 0, 0);
  }
}

__global__ __launch_bounds__(512, 4) void k_main(
    const float* __restrict__ x,
    const unsigned short* __restrict__ wv,
    const unsigned short* __restrict__ woutb,
    const float* __restrict__ cv,
    const float* __restrict__ bqkv,
    const float* __restrict__ bout,
    float* __restrict__ out)
{
  __shared__ __align__(16) unsigned short lds_u16[64*384];
  char* lds = (char*)lds_u16;
  const int bid = blockIdx.x;
  const int nb  = bid & 63;
  const int bp  = bid >> 6;
  const int b = bp >> 2, p = bp & 3;
  const int n0 = nb * 64;
  const int tid  = threadIdx.x;
  const int w    = tid >> 6;
  const int lane = tid & 63;
  const int g    = lane >> 4;
  const int l15  = lane & 15;

  const float* xb = x + (size_t)b*CC*PN + (size_t)p*NNN + n0 + lane;

  float s[12];
  stage_load(xb, w, 0, s);
  stage_write(lds, w, lane, 0, s);
  stage_load(xb, w, 1, s);
  __syncthreads();

  f32x4 acc[3][4];
  #pragma unroll
  for (int i = 0; i < 3; ++i)
    #pragma unroll
    for (int j = 0; j < 4; ++j) acc[i][j] = (f32x4){0.f,0.f,0.f,0.f};

  for (int c = 0; c < 4; ++c) {
    gemm_ks<3>(wv, lds, w, g, l15, 3*c, acc);
    if (c < 3) {
      stage_write(lds, w, lane, c+1, s);
      if (c < 2) stage_load(xb, w, c+2, s);
    }
    __syncthreads();
  }

  const float* cvp = cv + (size_t)bp*CC;
  #pragma unroll
  for (int mi = 0; mi < 3; ++mi) {
    const int m0 = 48*w + 16*mi + 4*g;
    const float* bv = bqkv + 385 + m0;
    const float b0 = bv[0], b1 = bv[1], b2 = bv[2], b3 = bv[3];
    const float4 cvv = *(const float4*)(cvp + m0);
    #pragma unroll
    for (int nt = 0; nt < 4; ++nt) {
      const int row = 16*nt + l15;
      const f32x4 t = acc[mi][nt];
      u16x4 pk = { f2bf(fmaxf(t[0]+b0, 0.f)*cvv.x), f2bf(fmaxf(t[1]+b1, 0.f)*cvv.y),
                   f2bf(fmaxf(t[2]+b2, 0.f)*cvv.z), f2bf(fmaxf(t[3]+b3, 0.f)*cvv.w) };
      const int byte0 = (row*768 + 2*m0) ^ (l15 << 4);
      *(u16x4*)(lds + byte0) = pk;
    }
  }
  __syncthreads();

  #pragma unroll
  for (int i = 0; i < 3; ++i)
    #pragma unroll
    for (int j = 0; j < 4; ++j) acc[i][j] = (f32x4){0.f,0.f,0.f,0.f};

  gemm_ks<12>(woutb, lds, w, g, l15, 0, acc);

  #pragma unroll
  for (int mi = 0; mi < 3; ++mi) {
    const int m0 = 48*w + 16*mi + 4*g;
    const float4 bo = *(const float4*)(bout + m0);
    #pragma unroll
    for (int nt = 0; nt < 4; ++nt) {
      const int nn = n0 + 16*nt + l15;
      const f32x4 t = acc[mi][nt];
      float* ob = out + ((size_t)b*CC + m0)*PN + (size_t)p*NNN + nn;
      ob[0]            = t[0] + bo.x;
      ob[(size_t)PN]   = t[1] + bo.y;
      ob[2*(size_t)PN] = t[2] + bo.z;
      ob[3*(size_t)PN] = t[3] + bo.w;
    }
  }
}

// ---------------------------------------------------------------------------
extern "C" void kernel_launch(void* const* d_in, const int* in_sizes, int n_in,
                              void* d_out, int out_size, void* d_ws, size_t ws_size,
                              hipStream_t stream) {
  const float* x    = (const float*)d_in[0];
  const float* wqkv = (const float*)d_in[1];
  const float* bqkv = (const float*)d_in[2];
  const float* wout = (const float*)d_in[3];
  const float* bout = (const float*)d_in[4];
  float* out = (float*)d_out;
  char* ws = (char*)d_ws;

  // fast-path workspace layout (~100.6 MB)
  const size_t OFF_XBF = 0;                       // 2048*49152 = 100663296
  const size_t OFF_Q   = 100663296;               // 524288
  const size_t OFF_PT  = 101187584;               // 3145728
  const size_t OFF_WVT = 104333312;               // 294912
  const size_t OFF_WOT = 104628224;               // 294912
  const size_t OFF_CV  = 104923136;               // 49152
  const size_t OFF_MT  = 104972288;               // 8192
  const size_t OFF_MZ  = 104980480;               // 256
  const size_t NEED    = 104980736;

  if (ws_size >= NEED) {
    unsigned short* xbf   = (unsigned short*)(ws + OFF_XBF);
    float* q              = (float*)(ws + OFF_Q);
    float* partial        = (float*)(ws + OFF_PT);
    unsigned short* wvt   = (unsigned short*)(ws + OFF_WVT);
    unsigned short* woutt = (unsigned short*)(ws + OFF_WOT);
    float* cvp            = (float*)(ws + OFF_CV);
    float* mt             = (float*)(ws + OFF_MT);
    float* MZ             = (float*)(ws + OFF_MZ);

    hipLaunchKernelGGL(k_pre,    dim3(2048), dim3(256), 0, stream, x, wqkv, xbf, q, partial, mt);
    hipLaunchKernelGGL(k_wcvt2,  dim3(1152), dim3(256), 0, stream, wqkv, wout, wvt, woutt);
    hipLaunchKernelGGL(k_qmz,    dim3(32),   dim3(256), 0, stream, q, bqkv, MZ);
    hipLaunchKernelGGL(k_cv3,    dim3(32),   dim3(384), 0, stream, partial, mt, MZ, bqkv, wqkv, cvp);
    hipLaunchKernelGGL(k_main2b, dim3(1024), dim3(768), 0, stream, xbf, wvt, woutt, cvp, bqkv, bout, out);
  } else {
    float* scores         = (float*)(ws);
    float* qpart          = (float*)(ws + 524288);
    float* xs             = (float*)(ws + 2621440);
    unsigned short* wv    = (unsigned short*)(ws + 2719744);
    unsigned short* woutb = (unsigned short*)(ws + 3014656);
    float* cvp            = (float*)(ws + 3309568);

    hipLaunchKernelGGL(k_qpart,   dim3(512),      dim3(256), 0, stream, x, wqkv, qpart);
    hipLaunchKernelGGL(k_wcvt,    dim3(1152),     dim3(256), 0, stream, wqkv, wout, wv, woutb);
    hipLaunchKernelGGL(k_softmax, dim3(32),       dim3(256), 0, stream, qpart, bqkv, scores);
    hipLaunchKernelGGL(k_xs,      dim3(CC, NBP),  dim3(256), 0, stream, x, scores, xs);
    hipLaunchKernelGGL(k_cv,      dim3(NBP),      dim3(384), 0, stream, wqkv, bqkv, xs, cvp);
    hipLaunchKernelGGL(k_main,    dim3(2048),     dim3(512), 0, stream, x, wv, woutb, cvp, bqkv, bout, out);
  }
}